// Round 9
// baseline (495.664 us; speedup 1.0000x reference)
//
#include <hip/hip_runtime.h>
#include <hip/hip_fp16.h>

// Problem constants (match reference)
#define IN_CH   128
#define HC      64      // channels per node at every layer boundary
#define NEG_SLOPE 0.2f

// counting-sort parameters: bucket = dst >> BSH (<=256 buckets), src in low 17 bits
#define BSH   9
#define NPB   512       // nodes per bucket = 1 << BSH
#define EPB   8192      // edges per binning block

// ---------------------------------------------------------------------------
// generic block scan kernels (used for the bucket-major countsT scan)
// ---------------------------------------------------------------------------
__global__ __launch_bounds__(256) void scan1_k(const int* __restrict__ deg, int* __restrict__ tmp,
                                               int* __restrict__ bsum, int n) {
    __shared__ int s[256];
    int tid = threadIdx.x;
    int i = blockIdx.x * 256 + tid;
    int v = (i < n) ? deg[i] : 0;
    s[tid] = v; __syncthreads();
    for (int o = 1; o < 256; o <<= 1) {
        int t = (tid >= o) ? s[tid - o] : 0;
        __syncthreads();
        s[tid] += t;
        __syncthreads();
    }
    if (i < n) tmp[i] = s[tid] - v;            // exclusive within block
    if (tid == 255) bsum[blockIdx.x] = s[255]; // block total
}

__global__ __launch_bounds__(512) void scan2_k(int* __restrict__ bsum, int nb) {
    __shared__ int s[512];
    int tid = threadIdx.x;
    int v = (tid < nb) ? bsum[tid] : 0;
    s[tid] = v; __syncthreads();
    for (int o = 1; o < 512; o <<= 1) {
        int t = (tid >= o) ? s[tid - o] : 0;
        __syncthreads();
        s[tid] += t;
        __syncthreads();
    }
    if (tid < nb) bsum[tid] = s[tid] - v;      // exclusive block offsets
}

__global__ __launch_bounds__(256) void combine_k(const int* __restrict__ tmp, const int* __restrict__ bsum,
                                                 int* __restrict__ base, int n) {
    int i = blockIdx.x * 256 + threadIdx.x;
    if (i < n) base[i] = tmp[i] + bsum[blockIdx.x];
}

// ---------------------------------------------------------------------------
// counting sort of edges by dst bucket — LDS-binned, no global atomic contention
// ---------------------------------------------------------------------------
__global__ __launch_bounds__(256) void csortA1_k(const int* __restrict__ ei, int* __restrict__ countsT,
                                                 int E, int nbuck, int neb) {
    __shared__ int cnt[256];
    cnt[threadIdx.x] = 0;
    __syncthreads();
    int base = blockIdx.x * EPB;
#pragma unroll
    for (int k = 0; k < EPB / 256; k++) {
        int i = base + k * 256 + threadIdx.x;
        if (i < E) atomicAdd(&cnt[ei[E + i] >> BSH], 1);
    }
    __syncthreads();
    if (threadIdx.x < nbuck) countsT[threadIdx.x * neb + blockIdx.x] = cnt[threadIdx.x];
}

__global__ __launch_bounds__(256) void csortA3_k(const int* __restrict__ ei, const int* __restrict__ baseT,
                                                 unsigned* __restrict__ pairs, int E, int nbuck, int neb) {
    __shared__ int cur[256];
    if (threadIdx.x < nbuck) cur[threadIdx.x] = baseT[threadIdx.x * neb + blockIdx.x];
    __syncthreads();
    int base = blockIdx.x * EPB;
#pragma unroll
    for (int k = 0; k < EPB / 256; k++) {
        int i = base + k * 256 + threadIdx.x;
        if (i < E) {
            int d = ei[E + i];
            int s = ei[i];
            int p = atomicAdd(&cur[d >> BSH], 1);
            pairs[p] = ((unsigned)(d & (NPB - 1)) << 17) | (unsigned)s;
        }
    }
}

// B: one block per bucket. Fused: per-node LDS histogram -> block scan ->
// node offsets (off[]) -> LDS-cursor ranking -> csr write.
__global__ __launch_bounds__(256) void csortB2_k(const unsigned* __restrict__ pairs, const int* __restrict__ baseT,
                                                 int* __restrict__ off, int* __restrict__ csr,
                                                 int N, int E, int nbuck, int neb) {
    __shared__ int cnt[NPB];
    __shared__ int cur[NPB];
    __shared__ int ps[256];
    int b = blockIdx.x;
    int tid = threadIdx.x;
    int rs = baseT[b * neb];
    int re = (b + 1 < nbuck) ? baseT[(b + 1) * neb] : E;

    cnt[tid] = 0; cnt[tid + 256] = 0;
    __syncthreads();
    for (int j = rs + tid; j < re; j += 256)
        atomicAdd(&cnt[pairs[j] >> 17], 1);
    __syncthreads();

    int c0 = cnt[2 * tid], c1 = cnt[2 * tid + 1];
    int pair = c0 + c1;
    ps[tid] = pair;
    __syncthreads();
    for (int o = 1; o < 256; o <<= 1) {
        int t = (tid >= o) ? ps[tid - o] : 0;
        __syncthreads();
        ps[tid] += t;
        __syncthreads();
    }
    int base0 = rs + ps[tid] - pair;
    int n0 = b * NPB + 2 * tid;
    cur[2 * tid] = base0;
    cur[2 * tid + 1] = base0 + c0;
    if (n0 < N)     off[n0] = base0;
    if (n0 + 1 < N) off[n0 + 1] = base0 + c0;
    if (b == nbuck - 1 && tid == 0) off[N] = E;
    __syncthreads();

    for (int j = rs + tid; j < re; j += 256) {
        unsigned v = pairs[j];
        int p = atomicAdd(&cur[v >> 17], 1);
        csr[p] = (int)(v & 0x1FFFF);
    }
}

// ---------------------------------------------------------------------------
// GEMM epilogue: attention logits + fp16 H-row store for one row.
// ---------------------------------------------------------------------------
template<int HEADS>
__device__ __forceinline__ void gemm_epilogue(const float4* acc, const float* __restrict__ a_s,
                                              const float* __restrict__ a_d, __half* __restrict__ H,
                                              float* __restrict__ ALS, float* __restrict__ ALD, int row) {
    if (HEADS == 2) {
        float s0 = 0.f, d0 = 0.f, s1 = 0.f, d1 = 0.f;
#pragma unroll
        for (int c4 = 0; c4 < 8; c4++) {
            s0 += acc[c4].x * a_s[4 * c4]     + acc[c4].y * a_s[4 * c4 + 1]
                + acc[c4].z * a_s[4 * c4 + 2] + acc[c4].w * a_s[4 * c4 + 3];
            d0 += acc[c4].x * a_d[4 * c4]     + acc[c4].y * a_d[4 * c4 + 1]
                + acc[c4].z * a_d[4 * c4 + 2] + acc[c4].w * a_d[4 * c4 + 3];
            s1 += acc[8 + c4].x * a_s[32 + 4 * c4]     + acc[8 + c4].y * a_s[32 + 4 * c4 + 1]
                + acc[8 + c4].z * a_s[32 + 4 * c4 + 2] + acc[8 + c4].w * a_s[32 + 4 * c4 + 3];
            d1 += acc[8 + c4].x * a_d[32 + 4 * c4]     + acc[8 + c4].y * a_d[32 + 4 * c4 + 1]
                + acc[8 + c4].z * a_d[32 + 4 * c4 + 2] + acc[8 + c4].w * a_d[32 + 4 * c4 + 3];
        }
        ALS[(size_t)row * 2]     = s0;
        ALS[(size_t)row * 2 + 1] = s1;
        ALD[(size_t)row * 2]     = d0;
        ALD[(size_t)row * 2 + 1] = d1;
    } else {
        float s0 = 0.f, d0 = 0.f;
#pragma unroll
        for (int c4 = 0; c4 < 16; c4++) {
            s0 += acc[c4].x * a_s[4 * c4]     + acc[c4].y * a_s[4 * c4 + 1]
                + acc[c4].z * a_s[4 * c4 + 2] + acc[c4].w * a_s[4 * c4 + 3];
            d0 += acc[c4].x * a_d[4 * c4]     + acc[c4].y * a_d[4 * c4 + 1]
                + acc[c4].z * a_d[4 * c4 + 2] + acc[c4].w * a_d[4 * c4 + 3];
        }
        ALS[row] = s0;
        ALD[row] = d0;
    }
    uint4* hv = (uint4*)(H + (size_t)row * 64);
#pragma unroll
    for (int c8 = 0; c8 < 8; c8++) {
        __half2 p0 = __floats2half2_rn(acc[2 * c8].x, acc[2 * c8].y);
        __half2 p1 = __floats2half2_rn(acc[2 * c8].z, acc[2 * c8].w);
        __half2 p2 = __floats2half2_rn(acc[2 * c8 + 1].x, acc[2 * c8 + 1].y);
        __half2 p3 = __floats2half2_rn(acc[2 * c8 + 1].z, acc[2 * c8 + 1].w);
        uint4 u;
        u.x = *(unsigned*)&p0;
        u.y = *(unsigned*)&p1;
        u.z = *(unsigned*)&p2;
        u.w = *(unsigned*)&p3;
        hv[c8] = u;
    }
}

// ---------------------------------------------------------------------------
// GEMM  H[n,64] = X[n,K] @ W[K,64]  + fused attention-logit epilogue.
// TWO ROWS PER THREAD: each LDS W-float4 read feeds 8 FMAs (was 4), halving
// the ds_read_b128 cycles per unit work (the measured bottleneck).
// ---------------------------------------------------------------------------
template<int K, int HEADS>
__global__ __launch_bounds__(256, 1) void gemm_al_k(const float* __restrict__ X, const float* __restrict__ W,
                                                    const float* __restrict__ a_s, const float* __restrict__ a_d,
                                                    __half* __restrict__ H, float* __restrict__ ALS,
                                                    float* __restrict__ ALD, int n) {
    __shared__ float4 lw[K * 16];
    int tid = threadIdx.x;
    const float4* wv = (const float4*)W;
#pragma unroll
    for (int j = 0; j < K * 16 / 256; j++)
        lw[tid + 256 * j] = wv[tid + 256 * j];
    __syncthreads();

    int row0 = blockIdx.x * 512 + tid;
    int row1 = row0 + 256;
    if (row0 >= n) return;
    bool r1v = row1 < n;

    float4 a0[16], a1[16];
#pragma unroll
    for (int c4 = 0; c4 < 16; c4++) {
        a0[c4] = make_float4(0.f, 0.f, 0.f, 0.f);
        a1[c4] = make_float4(0.f, 0.f, 0.f, 0.f);
    }

    const float4* xv0 = (const float4*)(X + (size_t)row0 * K);
    const float4* xv1 = (const float4*)(X + (size_t)(r1v ? row1 : row0) * K);
    float4 xa = xv0[0];
    float4 xb = xv1[0];
#pragma unroll 1
    for (int k4 = 0; k4 < K / 4; k4++) {
        float4 na = make_float4(0.f, 0.f, 0.f, 0.f);
        float4 nb = make_float4(0.f, 0.f, 0.f, 0.f);
        if (k4 + 1 < K / 4) { na = xv0[k4 + 1]; nb = xv1[k4 + 1]; }  // prefetch
#pragma unroll
        for (int j = 0; j < 4; j++) {
            float x0 = (j == 0) ? xa.x : (j == 1) ? xa.y : (j == 2) ? xa.z : xa.w;
            float x1 = (j == 0) ? xb.x : (j == 1) ? xb.y : (j == 2) ? xb.z : xb.w;
            const float4* wr = &lw[(k4 * 4 + j) * 16]; // wave-uniform LDS row
#pragma unroll
            for (int c4 = 0; c4 < 16; c4++) {
                float4 w = wr[c4];
                a0[c4].x += x0 * w.x; a0[c4].y += x0 * w.y;
                a0[c4].z += x0 * w.z; a0[c4].w += x0 * w.w;
                a1[c4].x += x1 * w.x; a1[c4].y += x1 * w.y;
                a1[c4].z += x1 * w.z; a1[c4].w += x1 * w.w;
            }
        }
        xa = na; xb = nb;
    }

    gemm_epilogue<HEADS>(a0, a_s, a_d, H, ALS, ALD, row0);
    if (r1v) gemm_epilogue<HEADS>(a1, a_s, a_d, H, ALS, ALD, row1);
}

// ---------------------------------------------------------------------------
// Aggregation: HALF2 lanes — 32 lanes per dst node, one wave = 2 nodes.
// Per-edge wave cost (addressing, exp, loads) is shared across 2 nodes.
// Predicated loop to max(lenA, lenB); invalid slots contribute w=0.
// ---------------------------------------------------------------------------
template<int HEADS, int RELU>
__global__ __launch_bounds__(256) void aggregate_k(const __half* __restrict__ H, const float* __restrict__ ALS,
                                                   const float* __restrict__ ALD, const int* __restrict__ off,
                                                   const int* __restrict__ csr, const float* __restrict__ bias,
                                                   float* __restrict__ OUT, int n) {
    int lane = threadIdx.x & 63;
    int wv   = threadIdx.x >> 6;
    int c2   = lane & 31;                 // channel-pair index: channels 2c2, 2c2+1
    int dst  = blockIdx.x * 8 + wv * 2 + (lane >> 5);
    bool alive = dst < n;
    int dsafe = alive ? dst : 0;
    int head = (HEADS == 2) ? (c2 >> 4) : 0;

    int b0 = off[dsafe];
    int b1 = alive ? off[dsafe + 1] : b0;
    float ald = ALD[(size_t)dsafe * HEADS + head];

    // self-loop contribution
    float e = ALS[(size_t)dsafe * HEADS + head] + ald;
    e = (e >= 0.f) ? e : NEG_SLOPE * e;
    float ee = alive ? __expf(e) : 0.f;
    float den = ee;
    const __half2* Hc = (const __half2*)H + c2;
    float2 hs = __half22float2(Hc[(size_t)dsafe * 32]);
    float accx = ee * hs.x, accy = ee * hs.y;

    int len = b1 - b0;
    int lmax = max(len, __shfl_xor(len, 32, 64));

    int j = 0;
    for (; j + 3 < lmax; j += 4) {
        int i0 = b0 + j;
        bool v0 = j     < len, v1 = j + 1 < len, v2 = j + 2 < len, v3 = j + 3 < len;
        int s0 = v0 ? csr[i0]     : 0;
        int s1 = v1 ? csr[i0 + 1] : 0;
        int s2 = v2 ? csr[i0 + 2] : 0;
        int s3 = v3 ? csr[i0 + 3] : 0;
        float a0 = ALS[(size_t)s0 * HEADS + head];
        float a1 = ALS[(size_t)s1 * HEADS + head];
        float a2 = ALS[(size_t)s2 * HEADS + head];
        float a3 = ALS[(size_t)s3 * HEADS + head];
        float2 h0 = __half22float2(Hc[(size_t)s0 * 32]);
        float2 h1 = __half22float2(Hc[(size_t)s1 * 32]);
        float2 h2 = __half22float2(Hc[(size_t)s2 * 32]);
        float2 h3 = __half22float2(Hc[(size_t)s3 * 32]);
        float e0 = a0 + ald; e0 = (e0 >= 0.f) ? e0 : NEG_SLOPE * e0;
        float e1 = a1 + ald; e1 = (e1 >= 0.f) ? e1 : NEG_SLOPE * e1;
        float e2 = a2 + ald; e2 = (e2 >= 0.f) ? e2 : NEG_SLOPE * e2;
        float e3 = a3 + ald; e3 = (e3 >= 0.f) ? e3 : NEG_SLOPE * e3;
        float w0 = v0 ? __expf(e0) : 0.f;
        float w1 = v1 ? __expf(e1) : 0.f;
        float w2 = v2 ? __expf(e2) : 0.f;
        float w3 = v3 ? __expf(e3) : 0.f;
        den += (w0 + w1) + (w2 + w3);
        accx += (w0 * h0.x + w1 * h1.x) + (w2 * h2.x + w3 * h3.x);
        accy += (w0 * h0.y + w1 * h1.y) + (w2 * h2.y + w3 * h3.y);
    }
    for (; j < lmax; j++) {
        bool v0 = j < len;
        int s0 = v0 ? csr[b0 + j] : 0;
        float a0 = ALS[(size_t)s0 * HEADS + head];
        float2 h0 = __half22float2(Hc[(size_t)s0 * 32]);
        float e0 = a0 + ald; e0 = (e0 >= 0.f) ? e0 : NEG_SLOPE * e0;
        float w0 = v0 ? __expf(e0) : 0.f;
        den += w0;
        accx += w0 * h0.x;
        accy += w0 * h0.y;
    }

    if (alive) {
        float2 bi = ((const float2*)bias)[c2];
        float rd = 1.f / den;
        float ox = accx * rd + bi.x;
        float oy = accy * rd + bi.y;
        if (RELU) {
            ox = (ox > 0.f) ? ox : 0.f;
            oy = (oy > 0.f) ? oy : 0.f;
        }
        ((float2*)OUT)[(size_t)dst * 32 + c2] = make_float2(ox, oy);
    }
}

// ---------------------------------------------------------------------------
extern "C" void kernel_launch(void* const* d_in, const int* in_sizes, int n_in,
                              void* d_out, int out_size, void* d_ws, size_t ws_size,
                              hipStream_t stream) {
    const float* x   = (const float*)d_in[0];
    const int*   ei  = (const int*)  d_in[1];
    const float* W1  = (const float*)d_in[2];
    const float* as1 = (const float*)d_in[3];
    const float* ad1 = (const float*)d_in[4];
    const float* b1  = (const float*)d_in[5];
    const float* W2  = (const float*)d_in[6];
    const float* as2 = (const float*)d_in[7];
    const float* ad2 = (const float*)d_in[8];
    const float* b2  = (const float*)d_in[9];
    const float* W3  = (const float*)d_in[10];
    const float* as3 = (const float*)d_in[11];
    const float* ad3 = (const float*)d_in[12];
    const float* b3  = (const float*)d_in[13];

    const int N = in_sizes[0] / IN_CH;
    const int E = in_sizes[1] / 2;
    const int NBUCK = (N + NPB - 1) >> BSH;              // 196 (<=256)
    const int NEB   = (E + EPB - 1) / EPB;               // 196 binning blocks
    const int NT    = NBUCK * NEB;                       // countsT elements (~38k)

    // workspace carve (256B aligned)
    char* p = (char*)d_ws;
    auto carve = [&](size_t bytes) {
        char* r = p;
        p += (bytes + 255) & ~(size_t)255;
        return r;
    };
    __half*   hbuf    = (__half*)  carve((size_t)N * HC * 2);
    float*    obuf    = (float*)   carve((size_t)N * HC * 4);
    float*    als     = (float*)   carve((size_t)N * 2 * 4);
    float*    ald     = (float*)   carve((size_t)N * 2 * 4);
    int*      off     = (int*)     carve((size_t)(N + 1) * 4);
    int*      tmp     = (int*)     carve((size_t)NT * 4);
    int*      bsum    = (int*)     carve((size_t)((NT + 255) / 256 + 1) * 4);
    int*      csr     = (int*)     carve((size_t)E * 4);
    unsigned* pairs   = (unsigned*)carve((size_t)E * 4);
    int*      countsT = (int*)     carve((size_t)NT * 4);
    int*      baseT   = (int*)     carve((size_t)NT * 4);

    const int NB2 = (N + 511) / 512;      // gemm blocks (2 rows/thread)
    const int NTB = (NT + 255) / 256;     // countsT-scan blocks (<=512)
    const int NW2 = (N + 7) / 8;          // aggregate: 2 nodes/wave, 4 waves/block

    // ---- CSR build (shared by all 3 layers); off[] fused into pass B ----
    csortA1_k<<<NEB, 256, 0, stream>>>(ei, countsT, E, NBUCK, NEB);
    scan1_k  <<<NTB, 256, 0, stream>>>(countsT, tmp, bsum, NT);
    scan2_k  <<<1, 512, 0, stream>>>(bsum, NTB);
    combine_k<<<NTB, 256, 0, stream>>>(tmp, bsum, baseT, NT);
    csortA3_k<<<NEB, 256, 0, stream>>>(ei, baseT, pairs, E, NBUCK, NEB);
    csortB2_k<<<NBUCK, 256, 0, stream>>>(pairs, baseT, off, csr, N, E, NBUCK, NEB);

    // ---- Layer 1: IN=128 -> 2x32 concat, relu ----
    gemm_al_k<128, 2><<<NB2, 256, 0, stream>>>(x, W1, as1, ad1, hbuf, als, ald, N);
    aggregate_k<2, 1><<<NW2, 256, 0, stream>>>(hbuf, als, ald, off, csr, b1, obuf, N);

    // ---- Layer 2: 64 -> 2x32 concat, relu ----
    gemm_al_k<64, 2><<<NB2, 256, 0, stream>>>(obuf, W2, as2, ad2, hbuf, als, ald, N);
    aggregate_k<2, 1><<<NW2, 256, 0, stream>>>(hbuf, als, ald, off, csr, b2, obuf, N);

    // ---- Layer 3: 64 -> 64, 1 head, mean(=identity), no relu ----
    gemm_al_k<64, 1><<<NB2, 256, 0, stream>>>(obuf, W3, as3, ad3, hbuf, als, ald, N);
    aggregate_k<1, 0><<<NW2, 256, 0, stream>>>(hbuf, als, ald, off, csr, b3, (float*)d_out, N);
}

// Round 10
// 419.691 us; speedup vs baseline: 1.1810x; 1.1810x over previous
//
#include <hip/hip_runtime.h>
#include <hip/hip_fp16.h>

// Problem constants (match reference)
#define IN_CH   128
#define HC      64      // channels per node at every layer boundary
#define NEG_SLOPE 0.2f

// counting-sort parameters: bucket = dst >> BSH (<=256 buckets), src in low 17 bits
#define BSH   9
#define NPB   512       // nodes per bucket = 1 << BSH
#define EPB   8192      // edges per binning block

// ---------------------------------------------------------------------------
// generic block scan kernels (used for the bucket-major countsT scan)
// ---------------------------------------------------------------------------
__global__ __launch_bounds__(256) void scan1_k(const int* __restrict__ deg, int* __restrict__ tmp,
                                               int* __restrict__ bsum, int n) {
    __shared__ int s[256];
    int tid = threadIdx.x;
    int i = blockIdx.x * 256 + tid;
    int v = (i < n) ? deg[i] : 0;
    s[tid] = v; __syncthreads();
    for (int o = 1; o < 256; o <<= 1) {
        int t = (tid >= o) ? s[tid - o] : 0;
        __syncthreads();
        s[tid] += t;
        __syncthreads();
    }
    if (i < n) tmp[i] = s[tid] - v;            // exclusive within block
    if (tid == 255) bsum[blockIdx.x] = s[255]; // block total
}

__global__ __launch_bounds__(512) void scan2_k(int* __restrict__ bsum, int nb) {
    __shared__ int s[512];
    int tid = threadIdx.x;
    int v = (tid < nb) ? bsum[tid] : 0;
    s[tid] = v; __syncthreads();
    for (int o = 1; o < 512; o <<= 1) {
        int t = (tid >= o) ? s[tid - o] : 0;
        __syncthreads();
        s[tid] += t;
        __syncthreads();
    }
    if (tid < nb) bsum[tid] = s[tid] - v;      // exclusive block offsets
}

__global__ __launch_bounds__(256) void combine_k(const int* __restrict__ tmp, const int* __restrict__ bsum,
                                                 int* __restrict__ base, int n) {
    int i = blockIdx.x * 256 + threadIdx.x;
    if (i < n) base[i] = tmp[i] + bsum[blockIdx.x];
}

// ---------------------------------------------------------------------------
// counting sort of edges by dst bucket — LDS-binned, no global atomic contention
// ---------------------------------------------------------------------------
__global__ __launch_bounds__(256) void csortA1_k(const int* __restrict__ ei, int* __restrict__ countsT,
                                                 int E, int nbuck, int neb) {
    __shared__ int cnt[256];
    cnt[threadIdx.x] = 0;
    __syncthreads();
    int base = blockIdx.x * EPB;
#pragma unroll
    for (int k = 0; k < EPB / 256; k++) {
        int i = base + k * 256 + threadIdx.x;
        if (i < E) atomicAdd(&cnt[ei[E + i] >> BSH], 1);
    }
    __syncthreads();
    if (threadIdx.x < nbuck) countsT[threadIdx.x * neb + blockIdx.x] = cnt[threadIdx.x];
}

__global__ __launch_bounds__(256) void csortA3_k(const int* __restrict__ ei, const int* __restrict__ baseT,
                                                 unsigned* __restrict__ pairs, int E, int nbuck, int neb) {
    __shared__ int cur[256];
    if (threadIdx.x < nbuck) cur[threadIdx.x] = baseT[threadIdx.x * neb + blockIdx.x];
    __syncthreads();
    int base = blockIdx.x * EPB;
#pragma unroll
    for (int k = 0; k < EPB / 256; k++) {
        int i = base + k * 256 + threadIdx.x;
        if (i < E) {
            int d = ei[E + i];
            int s = ei[i];
            int p = atomicAdd(&cur[d >> BSH], 1);
            pairs[p] = ((unsigned)(d & (NPB - 1)) << 17) | (unsigned)s;
        }
    }
}

// B: one block per bucket. Fused: per-node LDS histogram -> block scan ->
// node offsets (off[]) -> LDS-cursor ranking -> csr write. Also zero-pads
// csr[E..E+7] so the aggregate 8-slot batch can load unpredicated.
__global__ __launch_bounds__(256) void csortB2_k(const unsigned* __restrict__ pairs, const int* __restrict__ baseT,
                                                 int* __restrict__ off, int* __restrict__ csr,
                                                 int N, int E, int nbuck, int neb) {
    __shared__ int cnt[NPB];
    __shared__ int cur[NPB];
    __shared__ int ps[256];
    int b = blockIdx.x;
    int tid = threadIdx.x;
    int rs = baseT[b * neb];
    int re = (b + 1 < nbuck) ? baseT[(b + 1) * neb] : E;

    cnt[tid] = 0; cnt[tid + 256] = 0;
    __syncthreads();
    for (int j = rs + tid; j < re; j += 256)
        atomicAdd(&cnt[pairs[j] >> 17], 1);
    __syncthreads();

    int c0 = cnt[2 * tid], c1 = cnt[2 * tid + 1];
    int pair = c0 + c1;
    ps[tid] = pair;
    __syncthreads();
    for (int o = 1; o < 256; o <<= 1) {
        int t = (tid >= o) ? ps[tid - o] : 0;
        __syncthreads();
        ps[tid] += t;
        __syncthreads();
    }
    int base0 = rs + ps[tid] - pair;
    int n0 = b * NPB + 2 * tid;
    cur[2 * tid] = base0;
    cur[2 * tid + 1] = base0 + c0;
    if (n0 < N)     off[n0] = base0;
    if (n0 + 1 < N) off[n0 + 1] = base0 + c0;
    if (b == nbuck - 1 && tid == 0) off[N] = E;
    if (b == nbuck - 1 && tid < 8) csr[E + tid] = 0;   // pad for 8-slot batches
    __syncthreads();

    for (int j = rs + tid; j < re; j += 256) {
        unsigned v = pairs[j];
        int p = atomicAdd(&cur[v >> 17], 1);
        csr[p] = (int)(v & 0x1FFFF);
    }
}

// ---------------------------------------------------------------------------
// GEMM epilogue: attention logits + fp16 H-row store for one row.
// ---------------------------------------------------------------------------
template<int HEADS>
__device__ __forceinline__ void gemm_epilogue(const float4* acc, const float* __restrict__ a_s,
                                              const float* __restrict__ a_d, __half* __restrict__ H,
                                              float* __restrict__ ALS, float* __restrict__ ALD, int row) {
    if (HEADS == 2) {
        float s0 = 0.f, d0 = 0.f, s1 = 0.f, d1 = 0.f;
#pragma unroll
        for (int c4 = 0; c4 < 8; c4++) {
            s0 += acc[c4].x * a_s[4 * c4]     + acc[c4].y * a_s[4 * c4 + 1]
                + acc[c4].z * a_s[4 * c4 + 2] + acc[c4].w * a_s[4 * c4 + 3];
            d0 += acc[c4].x * a_d[4 * c4]     + acc[c4].y * a_d[4 * c4 + 1]
                + acc[c4].z * a_d[4 * c4 + 2] + acc[c4].w * a_d[4 * c4 + 3];
            s1 += acc[8 + c4].x * a_s[32 + 4 * c4]     + acc[8 + c4].y * a_s[32 + 4 * c4 + 1]
                + acc[8 + c4].z * a_s[32 + 4 * c4 + 2] + acc[8 + c4].w * a_s[32 + 4 * c4 + 3];
            d1 += acc[8 + c4].x * a_d[32 + 4 * c4]     + acc[8 + c4].y * a_d[32 + 4 * c4 + 1]
                + acc[8 + c4].z * a_d[32 + 4 * c4 + 2] + acc[8 + c4].w * a_d[32 + 4 * c4 + 3];
        }
        ALS[(size_t)row * 2]     = s0;
        ALS[(size_t)row * 2 + 1] = s1;
        ALD[(size_t)row * 2]     = d0;
        ALD[(size_t)row * 2 + 1] = d1;
    } else {
        float s0 = 0.f, d0 = 0.f;
#pragma unroll
        for (int c4 = 0; c4 < 16; c4++) {
            s0 += acc[c4].x * a_s[4 * c4]     + acc[c4].y * a_s[4 * c4 + 1]
                + acc[c4].z * a_s[4 * c4 + 2] + acc[c4].w * a_s[4 * c4 + 3];
            d0 += acc[c4].x * a_d[4 * c4]     + acc[c4].y * a_d[4 * c4 + 1]
                + acc[c4].z * a_d[4 * c4 + 2] + acc[c4].w * a_d[4 * c4 + 3];
        }
        ALS[row] = s0;
        ALD[row] = d0;
    }
    uint4* hv = (uint4*)(H + (size_t)row * 64);
#pragma unroll
    for (int c8 = 0; c8 < 8; c8++) {
        __half2 p0 = __floats2half2_rn(acc[2 * c8].x, acc[2 * c8].y);
        __half2 p1 = __floats2half2_rn(acc[2 * c8].z, acc[2 * c8].w);
        __half2 p2 = __floats2half2_rn(acc[2 * c8 + 1].x, acc[2 * c8 + 1].y);
        __half2 p3 = __floats2half2_rn(acc[2 * c8 + 1].z, acc[2 * c8 + 1].w);
        uint4 u;
        u.x = *(unsigned*)&p0;
        u.y = *(unsigned*)&p1;
        u.z = *(unsigned*)&p2;
        u.w = *(unsigned*)&p3;
        hv[c8] = u;
    }
}

// ---------------------------------------------------------------------------
// GEMM  H[n,64] = X[n,K] @ W[K,64]  + fused attention-logit epilogue.
// TWO ROWS PER THREAD; W staged in LDS (wave-uniform ds_read_b128).
// ---------------------------------------------------------------------------
template<int K, int HEADS>
__global__ __launch_bounds__(256, 1) void gemm_al_k(const float* __restrict__ X, const float* __restrict__ W,
                                                    const float* __restrict__ a_s, const float* __restrict__ a_d,
                                                    __half* __restrict__ H, float* __restrict__ ALS,
                                                    float* __restrict__ ALD, int n) {
    __shared__ float4 lw[K * 16];
    int tid = threadIdx.x;
    const float4* wv = (const float4*)W;
#pragma unroll
    for (int j = 0; j < K * 16 / 256; j++)
        lw[tid + 256 * j] = wv[tid + 256 * j];
    __syncthreads();

    int row0 = blockIdx.x * 512 + tid;
    int row1 = row0 + 256;
    if (row0 >= n) return;
    bool r1v = row1 < n;

    float4 a0[16], a1[16];
#pragma unroll
    for (int c4 = 0; c4 < 16; c4++) {
        a0[c4] = make_float4(0.f, 0.f, 0.f, 0.f);
        a1[c4] = make_float4(0.f, 0.f, 0.f, 0.f);
    }

    const float4* xv0 = (const float4*)(X + (size_t)row0 * K);
    const float4* xv1 = (const float4*)(X + (size_t)(r1v ? row1 : row0) * K);
    float4 xa = xv0[0];
    float4 xb = xv1[0];
#pragma unroll 1
    for (int k4 = 0; k4 < K / 4; k4++) {
        float4 na = make_float4(0.f, 0.f, 0.f, 0.f);
        float4 nb = make_float4(0.f, 0.f, 0.f, 0.f);
        if (k4 + 1 < K / 4) { na = xv0[k4 + 1]; nb = xv1[k4 + 1]; }  // prefetch
#pragma unroll
        for (int j = 0; j < 4; j++) {
            float x0 = (j == 0) ? xa.x : (j == 1) ? xa.y : (j == 2) ? xa.z : xa.w;
            float x1 = (j == 0) ? xb.x : (j == 1) ? xb.y : (j == 2) ? xb.z : xb.w;
            const float4* wr = &lw[(k4 * 4 + j) * 16]; // wave-uniform LDS row
#pragma unroll
            for (int c4 = 0; c4 < 16; c4++) {
                float4 w = wr[c4];
                a0[c4].x += x0 * w.x; a0[c4].y += x0 * w.y;
                a0[c4].z += x0 * w.z; a0[c4].w += x0 * w.w;
                a1[c4].x += x1 * w.x; a1[c4].y += x1 * w.y;
                a1[c4].z += x1 * w.z; a1[c4].w += x1 * w.w;
            }
        }
        xa = na; xb = nb;
    }

    gemm_epilogue<HEADS>(a0, a_s, a_d, H, ALS, ALD, row0);
    if (r1v) gemm_epilogue<HEADS>(a1, a_s, a_d, H, ALS, ALD, row1);
}

// ---------------------------------------------------------------------------
// Aggregation: HALF2 lanes (32 lanes/node, 2 nodes/wave) + 8-way unroll.
// csr zero-padded -> unpredicated batch loads; only the weight is masked.
// All gather indices 32-bit (saddr+voffset form, minimal addr VALU).
// ---------------------------------------------------------------------------
template<int HEADS, int RELU>
__global__ __launch_bounds__(256) void aggregate_k(const __half* __restrict__ H, const float* __restrict__ ALS,
                                                   const float* __restrict__ ALD, const int* __restrict__ off,
                                                   const int* __restrict__ csr, const float* __restrict__ bias,
                                                   float* __restrict__ OUT, int n) {
    int lane = threadIdx.x & 63;
    int wv   = threadIdx.x >> 6;
    int c2   = lane & 31;                 // channel-pair index: channels 2c2, 2c2+1
    int dst  = blockIdx.x * 8 + wv * 2 + (lane >> 5);
    bool alive = dst < n;
    int dsafe = alive ? dst : 0;
    int head = (HEADS == 2) ? (c2 >> 4) : 0;

    int b0 = off[dsafe];
    int b1 = alive ? off[dsafe + 1] : b0;
    float ald = ALD[dsafe * HEADS + head];

    // self-loop contribution
    float e = ALS[dsafe * HEADS + head] + ald;
    e = fmaxf(e, NEG_SLOPE * e);
    float ee = alive ? __expf(e) : 0.f;
    float den = ee;
    const __half2* Hc = (const __half2*)H;
    float2 hs = __half22float2(Hc[dsafe * 32 + c2]);
    float accx = ee * hs.x, accy = ee * hs.y;

    int len = b1 - b0;
    int lmax = max(len, __shfl_xor(len, 32, 64));

    int j = 0;
    for (; j + 7 < lmax; j += 8) {
        int i0 = b0 + j;
        int s[8];
#pragma unroll
        for (int k = 0; k < 8; k++) s[k] = csr[i0 + k];     // padded: always safe
        float al[8];
#pragma unroll
        for (int k = 0; k < 8; k++) al[k] = ALS[s[k] * HEADS + head];
        float2 h[8];
#pragma unroll
        for (int k = 0; k < 8; k++) h[k] = __half22float2(Hc[s[k] * 32 + c2]);
#pragma unroll
        for (int k = 0; k < 8; k++) {
            float ek = al[k] + ald;
            ek = fmaxf(ek, NEG_SLOPE * ek);
            float wk = (j + k < len) ? __expf(ek) : 0.f;
            den += wk;
            accx += wk * h[k].x;
            accy += wk * h[k].y;
        }
    }
    for (; j < lmax; j++) {
        int s0 = csr[b0 + j];
        float a0 = ALS[s0 * HEADS + head];
        float2 h0 = __half22float2(Hc[s0 * 32 + c2]);
        float e0 = a0 + ald;
        e0 = fmaxf(e0, NEG_SLOPE * e0);
        float w0 = (j < len) ? __expf(e0) : 0.f;
        den += w0;
        accx += w0 * h0.x;
        accy += w0 * h0.y;
    }

    if (alive) {
        float2 bi = ((const float2*)bias)[c2];
        float rd = 1.f / den;
        float ox = accx * rd + bi.x;
        float oy = accy * rd + bi.y;
        if (RELU) {
            ox = (ox > 0.f) ? ox : 0.f;
            oy = (oy > 0.f) ? oy : 0.f;
        }
        ((float2*)OUT)[dst * 32 + c2] = make_float2(ox, oy);
    }
}

// ---------------------------------------------------------------------------
extern "C" void kernel_launch(void* const* d_in, const int* in_sizes, int n_in,
                              void* d_out, int out_size, void* d_ws, size_t ws_size,
                              hipStream_t stream) {
    const float* x   = (const float*)d_in[0];
    const int*   ei  = (const int*)  d_in[1];
    const float* W1  = (const float*)d_in[2];
    const float* as1 = (const float*)d_in[3];
    const float* ad1 = (const float*)d_in[4];
    const float* b1  = (const float*)d_in[5];
    const float* W2  = (const float*)d_in[6];
    const float* as2 = (const float*)d_in[7];
    const float* ad2 = (const float*)d_in[8];
    const float* b2  = (const float*)d_in[9];
    const float* W3  = (const float*)d_in[10];
    const float* as3 = (const float*)d_in[11];
    const float* ad3 = (const float*)d_in[12];
    const float* b3  = (const float*)d_in[13];

    const int N = in_sizes[0] / IN_CH;
    const int E = in_sizes[1] / 2;
    const int NBUCK = (N + NPB - 1) >> BSH;              // 196 (<=256)
    const int NEB   = (E + EPB - 1) / EPB;               // 196 binning blocks
    const int NT    = NBUCK * NEB;                       // countsT elements (~38k)

    // workspace carve (256B aligned)
    char* p = (char*)d_ws;
    auto carve = [&](size_t bytes) {
        char* r = p;
        p += (bytes + 255) & ~(size_t)255;
        return r;
    };
    __half*   hbuf    = (__half*)  carve((size_t)N * HC * 2);
    float*    obuf    = (float*)   carve((size_t)N * HC * 4);
    float*    als     = (float*)   carve((size_t)N * 2 * 4);
    float*    ald     = (float*)   carve((size_t)N * 2 * 4);
    int*      off     = (int*)     carve((size_t)(N + 1) * 4);
    int*      tmp     = (int*)     carve((size_t)NT * 4);
    int*      bsum    = (int*)     carve((size_t)((NT + 255) / 256 + 1) * 4);
    int*      csr     = (int*)     carve((size_t)(E + 8) * 4);   // +8 zero pad
    unsigned* pairs   = (unsigned*)carve((size_t)E * 4);
    int*      countsT = (int*)     carve((size_t)NT * 4);
    int*      baseT   = (int*)     carve((size_t)NT * 4);

    const int NB2 = (N + 511) / 512;      // gemm blocks (2 rows/thread)
    const int NTB = (NT + 255) / 256;     // countsT-scan blocks (<=512)
    const int NW2 = (N + 7) / 8;          // aggregate: 2 nodes/wave, 4 waves/block

    // ---- CSR build (shared by all 3 layers); off[] fused into pass B ----
    csortA1_k<<<NEB, 256, 0, stream>>>(ei, countsT, E, NBUCK, NEB);
    scan1_k  <<<NTB, 256, 0, stream>>>(countsT, tmp, bsum, NT);
    scan2_k  <<<1, 512, 0, stream>>>(bsum, NTB);
    combine_k<<<NTB, 256, 0, stream>>>(tmp, bsum, baseT, NT);
    csortA3_k<<<NEB, 256, 0, stream>>>(ei, baseT, pairs, E, NBUCK, NEB);
    csortB2_k<<<NBUCK, 256, 0, stream>>>(pairs, baseT, off, csr, N, E, NBUCK, NEB);

    // ---- Layer 1: IN=128 -> 2x32 concat, relu ----
    gemm_al_k<128, 2><<<NB2, 256, 0, stream>>>(x, W1, as1, ad1, hbuf, als, ald, N);
    aggregate_k<2, 1><<<NW2, 256, 0, stream>>>(hbuf, als, ald, off, csr, b1, obuf, N);

    // ---- Layer 2: 64 -> 2x32 concat, relu ----
    gemm_al_k<64, 2><<<NB2, 256, 0, stream>>>(obuf, W2, as2, ad2, hbuf, als, ald, N);
    aggregate_k<2, 1><<<NW2, 256, 0, stream>>>(hbuf, als, ald, off, csr, b2, obuf, N);

    // ---- Layer 3: 64 -> 64, 1 head, mean(=identity), no relu ----
    gemm_al_k<64, 1><<<NB2, 256, 0, stream>>>(obuf, W3, as3, ad3, hbuf, als, ald, N);
    aggregate_k<1, 0><<<NW2, 256, 0, stream>>>(hbuf, als, ald, off, csr, b3, (float*)d_out, N);
}

// Round 11
// 349.841 us; speedup vs baseline: 1.4168x; 1.1997x over previous
//
#include <hip/hip_runtime.h>
#include <hip/hip_fp16.h>

// Problem constants (match reference)
#define IN_CH   128
#define HC      64      // channels per node at every layer boundary
#define NEG_SLOPE 0.2f

// counting-sort parameters: bucket = dst >> BSH (<=256 buckets), src in low 17 bits
#define BSH   9
#define NPB   512       // nodes per bucket = 1 << BSH
#define EPB   8192      // edges per binning block

typedef __attribute__((ext_vector_type(8))) _Float16 f16x8;
typedef __attribute__((ext_vector_type(4))) float    f32x4;

// ---------------------------------------------------------------------------
// generic block scan kernels (used for the bucket-major countsT scan)
// ---------------------------------------------------------------------------
__global__ __launch_bounds__(256) void scan1_k(const int* __restrict__ deg, int* __restrict__ tmp,
                                               int* __restrict__ bsum, int n) {
    __shared__ int s[256];
    int tid = threadIdx.x;
    int i = blockIdx.x * 256 + tid;
    int v = (i < n) ? deg[i] : 0;
    s[tid] = v; __syncthreads();
    for (int o = 1; o < 256; o <<= 1) {
        int t = (tid >= o) ? s[tid - o] : 0;
        __syncthreads();
        s[tid] += t;
        __syncthreads();
    }
    if (i < n) tmp[i] = s[tid] - v;            // exclusive within block
    if (tid == 255) bsum[blockIdx.x] = s[255]; // block total
}

__global__ __launch_bounds__(512) void scan2_k(int* __restrict__ bsum, int nb) {
    __shared__ int s[512];
    int tid = threadIdx.x;
    int v = (tid < nb) ? bsum[tid] : 0;
    s[tid] = v; __syncthreads();
    for (int o = 1; o < 512; o <<= 1) {
        int t = (tid >= o) ? s[tid - o] : 0;
        __syncthreads();
        s[tid] += t;
        __syncthreads();
    }
    if (tid < nb) bsum[tid] = s[tid] - v;      // exclusive block offsets
}

__global__ __launch_bounds__(256) void combine_k(const int* __restrict__ tmp, const int* __restrict__ bsum,
                                                 int* __restrict__ base, int n) {
    int i = blockIdx.x * 256 + threadIdx.x;
    if (i < n) base[i] = tmp[i] + bsum[blockIdx.x];
}

// ---------------------------------------------------------------------------
// counting sort of edges by dst bucket — LDS-binned, no global atomic contention
// ---------------------------------------------------------------------------
__global__ __launch_bounds__(256) void csortA1_k(const int* __restrict__ ei, int* __restrict__ countsT,
                                                 int E, int nbuck, int neb) {
    __shared__ int cnt[256];
    cnt[threadIdx.x] = 0;
    __syncthreads();
    int base = blockIdx.x * EPB;
#pragma unroll
    for (int k = 0; k < EPB / 256; k++) {
        int i = base + k * 256 + threadIdx.x;
        if (i < E) atomicAdd(&cnt[ei[E + i] >> BSH], 1);
    }
    __syncthreads();
    if (threadIdx.x < nbuck) countsT[threadIdx.x * neb + blockIdx.x] = cnt[threadIdx.x];
}

__global__ __launch_bounds__(256) void csortA3_k(const int* __restrict__ ei, const int* __restrict__ baseT,
                                                 unsigned* __restrict__ pairs, int E, int nbuck, int neb) {
    __shared__ int cur[256];
    if (threadIdx.x < nbuck) cur[threadIdx.x] = baseT[threadIdx.x * neb + blockIdx.x];
    __syncthreads();
    int base = blockIdx.x * EPB;
#pragma unroll
    for (int k = 0; k < EPB / 256; k++) {
        int i = base + k * 256 + threadIdx.x;
        if (i < E) {
            int d = ei[E + i];
            int s = ei[i];
            int p = atomicAdd(&cur[d >> BSH], 1);
            pairs[p] = ((unsigned)(d & (NPB - 1)) << 17) | (unsigned)s;
        }
    }
}

// B: one block per bucket. Fused: per-node LDS histogram -> block scan ->
// node offsets (off[]) -> LDS-cursor ranking -> csr write. Zero-pads csr[E..E+7].
__global__ __launch_bounds__(256) void csortB2_k(const unsigned* __restrict__ pairs, const int* __restrict__ baseT,
                                                 int* __restrict__ off, int* __restrict__ csr,
                                                 int N, int E, int nbuck, int neb) {
    __shared__ int cnt[NPB];
    __shared__ int cur[NPB];
    __shared__ int ps[256];
    int b = blockIdx.x;
    int tid = threadIdx.x;
    int rs = baseT[b * neb];
    int re = (b + 1 < nbuck) ? baseT[(b + 1) * neb] : E;

    cnt[tid] = 0; cnt[tid + 256] = 0;
    __syncthreads();
    for (int j = rs + tid; j < re; j += 256)
        atomicAdd(&cnt[pairs[j] >> 17], 1);
    __syncthreads();

    int c0 = cnt[2 * tid], c1 = cnt[2 * tid + 1];
    int pair = c0 + c1;
    ps[tid] = pair;
    __syncthreads();
    for (int o = 1; o < 256; o <<= 1) {
        int t = (tid >= o) ? ps[tid - o] : 0;
        __syncthreads();
        ps[tid] += t;
        __syncthreads();
    }
    int base0 = rs + ps[tid] - pair;
    int n0 = b * NPB + 2 * tid;
    cur[2 * tid] = base0;
    cur[2 * tid + 1] = base0 + c0;
    if (n0 < N)     off[n0] = base0;
    if (n0 + 1 < N) off[n0 + 1] = base0 + c0;
    if (b == nbuck - 1 && tid == 0) off[N] = E;
    if (b == nbuck - 1 && tid < 8) csr[E + tid] = 0;   // pad for 8-slot batches
    __syncthreads();

    for (int j = rs + tid; j < re; j += 256) {
        unsigned v = pairs[j];
        int p = atomicAdd(&cur[v >> 17], 1);
        csr[p] = (int)(v & 0x1FFFF);
    }
}

// ---------------------------------------------------------------------------
// W pre-pack: fp32 W[K][64] -> fp16 B-fragment order for mfma_f32_16x16x32_f16.
// B-frag: lane holds B[k = quad*8+j][n = lane&15] for tile t, kstep s.
// P[((s*4+t)*64 + lane)*8 + j] = W[s*32 + (lane>>4)*8 + j][t*16 + (lane&15)]
// ---------------------------------------------------------------------------
__global__ __launch_bounds__(256) void wpack_k(const float* __restrict__ W, _Float16* __restrict__ P, int total) {
    int o = blockIdx.x * 256 + threadIdx.x;
    if (o >= total) return;
    int j = o & 7, l = (o >> 3) & 63, t = (o >> 9) & 3, s = o >> 11;
    int row = s * 32 + ((l >> 4) << 3) + j;
    int col = (t << 4) + (l & 15);
    P[o] = (_Float16)W[row * 64 + col];
}

// ---------------------------------------------------------------------------
// MFMA GEMM: H[n,64] = X[n,K] @ W[K,64] (fp16 in, fp32 acc) + logits epilogue.
// One wave = 16 rows x 64 cols: 4 col-tiles, K/32 k-steps, 16x16x32_f16 MFMA.
// A: m=lane&15, k=quad*8+j (X rows, converted fp32->fp16 in-register).
// C/D: col=lane&15, row=quad*4+reg. Requires n % 16 == 0 (N=100000 ok).
// ---------------------------------------------------------------------------
template<int K, int HEADS>
__global__ __launch_bounds__(256) void gemm_mfma_k(const float* __restrict__ X, const _Float16* __restrict__ P,
                                                   const float* __restrict__ a_s, const float* __restrict__ a_d,
                                                   __half* __restrict__ H, float* __restrict__ ALS,
                                                   float* __restrict__ ALD, int n) {
    __shared__ _Float16 lh[4][16 * 72];   // per-wave transpose buffer, stride 72 halves
    int tid = threadIdx.x;
    int wv = tid >> 6, lane = tid & 63;
    int wid = blockIdx.x * 4 + wv;
    int rowbase = wid << 4;
    if (rowbase >= n) return;
    int q = lane >> 4, cl = lane & 15;

    // preload all B fragments (K/32 ksteps x 4 tiles), coalesced dwordx4
    f16x8 b[K / 32][4];
    const f16x8* Pv = (const f16x8*)P;
#pragma unroll
    for (int s = 0; s < K / 32; s++)
#pragma unroll
        for (int t = 0; t < 4; t++)
            b[s][t] = Pv[(s * 4 + t) * 64 + lane];

    f32x4 c[4];
#pragma unroll
    for (int t = 0; t < 4; t++) c[t] = (f32x4){0.f, 0.f, 0.f, 0.f};

    const float* xrow = X + (size_t)(rowbase + cl) * K + q * 8;
#pragma unroll
    for (int s = 0; s < K / 32; s++) {
        float4 x0 = *(const float4*)(xrow + s * 32);
        float4 x1 = *(const float4*)(xrow + s * 32 + 4);
        f16x8 a;
        a[0] = (_Float16)x0.x; a[1] = (_Float16)x0.y; a[2] = (_Float16)x0.z; a[3] = (_Float16)x0.w;
        a[4] = (_Float16)x1.x; a[5] = (_Float16)x1.y; a[6] = (_Float16)x1.z; a[7] = (_Float16)x1.w;
#pragma unroll
        for (int t = 0; t < 4; t++)
            c[t] = __builtin_amdgcn_mfma_f32_16x16x32_f16(a, b[s][t], c[t], 0, 0, 0);
    }

    // ---- logits epilogue: lane holds D[row=q*4+reg][col=t*16+cl] ----
    if (HEADS == 2) {
        float as0 = a_s[cl], as1 = a_s[16 + cl], as2 = a_s[32 + cl], as3 = a_s[48 + cl];
        float ad0 = a_d[cl], ad1 = a_d[16 + cl], ad2 = a_d[32 + cl], ad3 = a_d[48 + cl];
#pragma unroll
        for (int reg = 0; reg < 4; reg++) {
            float s0 = c[0][reg] * as0 + c[1][reg] * as1;
            float d0 = c[0][reg] * ad0 + c[1][reg] * ad1;
            float s1 = c[2][reg] * as2 + c[3][reg] * as3;
            float d1 = c[2][reg] * ad2 + c[3][reg] * ad3;
#pragma unroll
            for (int m = 1; m <= 8; m <<= 1) {
                s0 += __shfl_xor(s0, m, 64);
                d0 += __shfl_xor(d0, m, 64);
                s1 += __shfl_xor(s1, m, 64);
                d1 += __shfl_xor(d1, m, 64);
            }
            if (cl == 0) {
                int row = rowbase + q * 4 + reg;
                ALS[row * 2]     = s0;
                ALS[row * 2 + 1] = s1;
                ALD[row * 2]     = d0;
                ALD[row * 2 + 1] = d1;
            }
        }
    } else {
        float as0 = a_s[cl], as1 = a_s[16 + cl], as2 = a_s[32 + cl], as3 = a_s[48 + cl];
        float ad0 = a_d[cl], ad1 = a_d[16 + cl], ad2 = a_d[32 + cl], ad3 = a_d[48 + cl];
#pragma unroll
        for (int reg = 0; reg < 4; reg++) {
            float s0 = c[0][reg] * as0 + c[1][reg] * as1 + c[2][reg] * as2 + c[3][reg] * as3;
            float d0 = c[0][reg] * ad0 + c[1][reg] * ad1 + c[2][reg] * ad2 + c[3][reg] * ad3;
#pragma unroll
            for (int m = 1; m <= 8; m <<= 1) {
                s0 += __shfl_xor(s0, m, 64);
                d0 += __shfl_xor(d0, m, 64);
            }
            if (cl == 0) {
                int row = rowbase + q * 4 + reg;
                ALS[row] = s0;
                ALD[row] = d0;
            }
        }
    }

    // ---- H store: linearize via per-wave LDS (stride 72 -> ~2-way max) ----
    _Float16* L = lh[wv];
#pragma unroll
    for (int t = 0; t < 4; t++)
#pragma unroll
        for (int reg = 0; reg < 4; reg++)
            L[(q * 4 + reg) * 72 + t * 16 + cl] = (_Float16)c[t][reg];
    __builtin_amdgcn_s_waitcnt(0);   // drain lgkm before re-reading own wave's LDS
    int rr = lane >> 2, seg = lane & 3;
    uint4 v0 = *(const uint4*)((const char*)L + rr * 144 + seg * 32);
    uint4 v1 = *(const uint4*)((const char*)L + rr * 144 + seg * 32 + 16);
    char* hb = (char*)(H + (size_t)rowbase * 64);
    *(uint4*)(hb + rr * 128 + seg * 32)      = v0;
    *(uint4*)(hb + rr * 128 + seg * 32 + 16) = v1;
}

// ---------------------------------------------------------------------------
// Aggregation: HALF2 lanes (32 lanes/node, 2 nodes/wave) + 8-way unroll.
// csr zero-padded -> unpredicated batch loads; only the weight is masked.
// ---------------------------------------------------------------------------
template<int HEADS, int RELU>
__global__ __launch_bounds__(256) void aggregate_k(const __half* __restrict__ H, const float* __restrict__ ALS,
                                                   const float* __restrict__ ALD, const int* __restrict__ off,
                                                   const int* __restrict__ csr, const float* __restrict__ bias,
                                                   float* __restrict__ OUT, int n) {
    int lane = threadIdx.x & 63;
    int wv   = threadIdx.x >> 6;
    int c2   = lane & 31;                 // channel-pair index: channels 2c2, 2c2+1
    int dst  = blockIdx.x * 8 + wv * 2 + (lane >> 5);
    bool alive = dst < n;
    int dsafe = alive ? dst : 0;
    int head = (HEADS == 2) ? (c2 >> 4) : 0;

    int b0 = off[dsafe];
    int b1 = alive ? off[dsafe + 1] : b0;
    float ald = ALD[dsafe * HEADS + head];

    // self-loop contribution
    float e = ALS[dsafe * HEADS + head] + ald;
    e = fmaxf(e, NEG_SLOPE * e);
    float ee = alive ? __expf(e) : 0.f;
    float den = ee;
    const __half2* Hc = (const __half2*)H;
    float2 hs = __half22float2(Hc[dsafe * 32 + c2]);
    float accx = ee * hs.x, accy = ee * hs.y;

    int len = b1 - b0;
    int lmax = max(len, __shfl_xor(len, 32, 64));

    int j = 0;
    for (; j + 7 < lmax; j += 8) {
        int i0 = b0 + j;
        int s[8];
#pragma unroll
        for (int k = 0; k < 8; k++) s[k] = csr[i0 + k];     // padded: always safe
        float al[8];
#pragma unroll
        for (int k = 0; k < 8; k++) al[k] = ALS[s[k] * HEADS + head];
        float2 h[8];
#pragma unroll
        for (int k = 0; k < 8; k++) h[k] = __half22float2(Hc[s[k] * 32 + c2]);
#pragma unroll
        for (int k = 0; k < 8; k++) {
            float ek = al[k] + ald;
            ek = fmaxf(ek, NEG_SLOPE * ek);
            float wk = (j + k < len) ? __expf(ek) : 0.f;
            den += wk;
            accx += wk * h[k].x;
            accy += wk * h[k].y;
        }
    }
    for (; j < lmax; j++) {
        int s0 = csr[b0 + j];
        float a0 = ALS[s0 * HEADS + head];
        float2 h0 = __half22float2(Hc[s0 * 32 + c2]);
        float e0 = a0 + ald;
        e0 = fmaxf(e0, NEG_SLOPE * e0);
        float w0 = (j < len) ? __expf(e0) : 0.f;
        den += w0;
        accx += w0 * h0.x;
        accy += w0 * h0.y;
    }

    if (alive) {
        float2 bi = ((const float2*)bias)[c2];
        float rd = 1.f / den;
        float ox = accx * rd + bi.x;
        float oy = accy * rd + bi.y;
        if (RELU) {
            ox = (ox > 0.f) ? ox : 0.f;
            oy = (oy > 0.f) ? oy : 0.f;
        }
        ((float2*)OUT)[dst * 32 + c2] = make_float2(ox, oy);
    }
}

// ---------------------------------------------------------------------------
extern "C" void kernel_launch(void* const* d_in, const int* in_sizes, int n_in,
                              void* d_out, int out_size, void* d_ws, size_t ws_size,
                              hipStream_t stream) {
    const float* x   = (const float*)d_in[0];
    const int*   ei  = (const int*)  d_in[1];
    const float* W1  = (const float*)d_in[2];
    const float* as1 = (const float*)d_in[3];
    const float* ad1 = (const float*)d_in[4];
    const float* b1  = (const float*)d_in[5];
    const float* W2  = (const float*)d_in[6];
    const float* as2 = (const float*)d_in[7];
    const float* ad2 = (const float*)d_in[8];
    const float* b2  = (const float*)d_in[9];
    const float* W3  = (const float*)d_in[10];
    const float* as3 = (const float*)d_in[11];
    const float* ad3 = (const float*)d_in[12];
    const float* b3  = (const float*)d_in[13];

    const int N = in_sizes[0] / IN_CH;
    const int E = in_sizes[1] / 2;
    const int NBUCK = (N + NPB - 1) >> BSH;              // 196 (<=256)
    const int NEB   = (E + EPB - 1) / EPB;               // 196 binning blocks
    const int NT    = NBUCK * NEB;                       // countsT elements (~38k)

    // workspace carve (256B aligned)
    char* p = (char*)d_ws;
    auto carve = [&](size_t bytes) {
        char* r = p;
        p += (bytes + 255) & ~(size_t)255;
        return r;
    };
    __half*    hbuf    = (__half*)   carve((size_t)N * HC * 2);
    float*     obuf    = (float*)    carve((size_t)N * HC * 4);
    float*     als     = (float*)    carve((size_t)N * 2 * 4);
    float*     ald     = (float*)    carve((size_t)N * 2 * 4);
    int*       off     = (int*)      carve((size_t)(N + 1) * 4);
    int*       tmp     = (int*)      carve((size_t)NT * 4);
    int*       bsum    = (int*)      carve((size_t)((NT + 255) / 256 + 1) * 4);
    int*       csr     = (int*)      carve((size_t)(E + 8) * 4);   // +8 zero pad
    unsigned*  pairs   = (unsigned*) carve((size_t)E * 4);
    int*       countsT = (int*)      carve((size_t)NT * 4);
    int*       baseT   = (int*)      carve((size_t)NT * 4);
    _Float16*  wp1     = (_Float16*) carve((size_t)IN_CH * 64 * 2);
    _Float16*  wp2     = (_Float16*) carve((size_t)64 * 64 * 2);
    _Float16*  wp3     = (_Float16*) carve((size_t)64 * 64 * 2);

    const int NTB = (NT + 255) / 256;     // countsT-scan blocks (<=512)
    const int NW2 = (N + 7) / 8;          // aggregate: 2 nodes/wave, 4 waves/block
    const int NBM = (N / 16 + 3) / 4;     // mfma gemm: 16 rows/wave, 4 waves/block

    // ---- W fragment pre-pack (fp32 -> fp16 B-frag order) ----
    wpack_k<<<(IN_CH * 64) / 256, 256, 0, stream>>>(W1, wp1, IN_CH * 64);
    wpack_k<<<(64 * 64) / 256, 256, 0, stream>>>(W2, wp2, 64 * 64);
    wpack_k<<<(64 * 64) / 256, 256, 0, stream>>>(W3, wp3, 64 * 64);

    // ---- CSR build (shared by all 3 layers); off[] fused into pass B ----
    csortA1_k<<<NEB, 256, 0, stream>>>(ei, countsT, E, NBUCK, NEB);
    scan1_k  <<<NTB, 256, 0, stream>>>(countsT, tmp, bsum, NT);
    scan2_k  <<<1, 512, 0, stream>>>(bsum, NTB);
    combine_k<<<NTB, 256, 0, stream>>>(tmp, bsum, baseT, NT);
    csortA3_k<<<NEB, 256, 0, stream>>>(ei, baseT, pairs, E, NBUCK, NEB);
    csortB2_k<<<NBUCK, 256, 0, stream>>>(pairs, baseT, off, csr, N, E, NBUCK, NEB);

    // ---- Layer 1: IN=128 -> 2x32 concat, relu ----
    gemm_mfma_k<128, 2><<<NBM, 256, 0, stream>>>(x, wp1, as1, ad1, hbuf, als, ald, N);
    aggregate_k<2, 1>  <<<NW2, 256, 0, stream>>>(hbuf, als, ald, off, csr, b1, obuf, N);

    // ---- Layer 2: 64 -> 2x32 concat, relu ----
    gemm_mfma_k<64, 2><<<NBM, 256, 0, stream>>>(obuf, wp2, as2, ad2, hbuf, als, ald, N);
    aggregate_k<2, 1> <<<NW2, 256, 0, stream>>>(hbuf, als, ald, off, csr, b2, obuf, N);

    // ---- Layer 3: 64 -> 64, 1 head, mean(=identity), no relu ----
    gemm_mfma_k<64, 1><<<NBM, 256, 0, stream>>>(obuf, wp3, as3, ad3, hbuf, als, ald, N);
    aggregate_k<1, 0> <<<NW2, 256, 0, stream>>>(hbuf, als, ald, off, csr, b3, (float*)d_out, N);
}

// Round 12
// 334.752 us; speedup vs baseline: 1.4807x; 1.0451x over previous
//
#include <hip/hip_runtime.h>
#include <hip/hip_fp16.h>

// Problem constants (match reference)
#define IN_CH   128
#define HC      64      // channels per node at every layer boundary
#define NEG_SLOPE 0.2f

// counting-sort parameters: bucket = dst >> BSH (<=256 buckets), src in low 17 bits
#define BSH   9
#define NPB   512       // nodes per bucket = 1 << BSH
#define EPB   8192      // edges per binning block
#define DBIN  64        // degree bins for node degree-sort (clamped)

typedef __attribute__((ext_vector_type(8))) _Float16 f16x8;
typedef __attribute__((ext_vector_type(4))) float    f32x4;

// ---------------------------------------------------------------------------
// generic block scan kernels
// ---------------------------------------------------------------------------
__global__ __launch_bounds__(256) void scan1_k(const int* __restrict__ deg, int* __restrict__ tmp,
                                               int* __restrict__ bsum, int n) {
    __shared__ int s[256];
    int tid = threadIdx.x;
    int i = blockIdx.x * 256 + tid;
    int v = (i < n) ? deg[i] : 0;
    s[tid] = v; __syncthreads();
    for (int o = 1; o < 256; o <<= 1) {
        int t = (tid >= o) ? s[tid - o] : 0;
        __syncthreads();
        s[tid] += t;
        __syncthreads();
    }
    if (i < n) tmp[i] = s[tid] - v;            // exclusive within block
    if (tid == 255) bsum[blockIdx.x] = s[255]; // block total
}

__global__ __launch_bounds__(512) void scan2_k(int* __restrict__ bsum, int nb) {
    __shared__ int s[512];
    int tid = threadIdx.x;
    int v = (tid < nb) ? bsum[tid] : 0;
    s[tid] = v; __syncthreads();
    for (int o = 1; o < 512; o <<= 1) {
        int t = (tid >= o) ? s[tid - o] : 0;
        __syncthreads();
        s[tid] += t;
        __syncthreads();
    }
    if (tid < nb) bsum[tid] = s[tid] - v;      // exclusive block offsets
}

__global__ __launch_bounds__(256) void combine_k(const int* __restrict__ tmp, const int* __restrict__ bsum,
                                                 int* __restrict__ base, int n) {
    int i = blockIdx.x * 256 + threadIdx.x;
    if (i < n) base[i] = tmp[i] + bsum[blockIdx.x];
}

// ---------------------------------------------------------------------------
// counting sort of edges by dst bucket — LDS-binned, no global atomic contention
// ---------------------------------------------------------------------------
__global__ __launch_bounds__(256) void csortA1_k(const int* __restrict__ ei, int* __restrict__ countsT,
                                                 int E, int nbuck, int neb) {
    __shared__ int cnt[256];
    cnt[threadIdx.x] = 0;
    __syncthreads();
    int base = blockIdx.x * EPB;
#pragma unroll
    for (int k = 0; k < EPB / 256; k++) {
        int i = base + k * 256 + threadIdx.x;
        if (i < E) atomicAdd(&cnt[ei[E + i] >> BSH], 1);
    }
    __syncthreads();
    if (threadIdx.x < nbuck) countsT[threadIdx.x * neb + blockIdx.x] = cnt[threadIdx.x];
}

__global__ __launch_bounds__(256) void csortA3_k(const int* __restrict__ ei, const int* __restrict__ baseT,
                                                 unsigned* __restrict__ pairs, int E, int nbuck, int neb) {
    __shared__ int cur[256];
    if (threadIdx.x < nbuck) cur[threadIdx.x] = baseT[threadIdx.x * neb + blockIdx.x];
    __syncthreads();
    int base = blockIdx.x * EPB;
#pragma unroll
    for (int k = 0; k < EPB / 256; k++) {
        int i = base + k * 256 + threadIdx.x;
        if (i < E) {
            int d = ei[E + i];
            int s = ei[i];
            int p = atomicAdd(&cur[d >> BSH], 1);
            pairs[p] = ((unsigned)(d & (NPB - 1)) << 17) | (unsigned)s;
        }
    }
}

// B: one block per bucket. Fused: per-node LDS histogram -> block scan ->
// node offsets (off[]) -> LDS-cursor ranking -> csr write. Zero-pads csr[E..E+63].
__global__ __launch_bounds__(256) void csortB2_k(const unsigned* __restrict__ pairs, const int* __restrict__ baseT,
                                                 int* __restrict__ off, int* __restrict__ csr,
                                                 int N, int E, int nbuck, int neb) {
    __shared__ int cnt[NPB];
    __shared__ int cur[NPB];
    __shared__ int ps[256];
    int b = blockIdx.x;
    int tid = threadIdx.x;
    int rs = baseT[b * neb];
    int re = (b + 1 < nbuck) ? baseT[(b + 1) * neb] : E;

    cnt[tid] = 0; cnt[tid + 256] = 0;
    __syncthreads();
    for (int j = rs + tid; j < re; j += 256)
        atomicAdd(&cnt[pairs[j] >> 17], 1);
    __syncthreads();

    int c0 = cnt[2 * tid], c1 = cnt[2 * tid + 1];
    int pair = c0 + c1;
    ps[tid] = pair;
    __syncthreads();
    for (int o = 1; o < 256; o <<= 1) {
        int t = (tid >= o) ? ps[tid - o] : 0;
        __syncthreads();
        ps[tid] += t;
        __syncthreads();
    }
    int base0 = rs + ps[tid] - pair;
    int n0 = b * NPB + 2 * tid;
    cur[2 * tid] = base0;
    cur[2 * tid + 1] = base0 + c0;
    if (n0 < N)     off[n0] = base0;
    if (n0 + 1 < N) off[n0 + 1] = base0 + c0;
    if (b == nbuck - 1 && tid == 0) off[N] = E;
    if (b == nbuck - 1 && tid < 64) csr[E + tid] = 0;   // pad for batched reads
    __syncthreads();

    for (int j = rs + tid; j < re; j += 256) {
        unsigned v = pairs[j];
        int p = atomicAdd(&cur[v >> 17], 1);
        csr[p] = (int)(v & 0x1FFFF);
    }
}

// ---------------------------------------------------------------------------
// Node degree-sort (counting sort by clamped degree) — groups equal-length
// nodes into the same wave for the aggregate (kills max-of-4 pairing waste).
// ---------------------------------------------------------------------------
__global__ __launch_bounds__(256) void dhist_k(const int* __restrict__ off, int* __restrict__ countsD,
                                               int N, int nb) {
    __shared__ int cnt[DBIN];
    if (threadIdx.x < DBIN) cnt[threadIdx.x] = 0;
    __syncthreads();
    int i = blockIdx.x * 256 + threadIdx.x;
    if (i < N) {
        int d = min(off[i + 1] - off[i], DBIN - 1);
        atomicAdd(&cnt[d], 1);
    }
    __syncthreads();
    if (threadIdx.x < DBIN) countsD[threadIdx.x * nb + blockIdx.x] = cnt[threadIdx.x];
}

__global__ __launch_bounds__(256) void drank_k(const int* __restrict__ off, const int* __restrict__ baseD,
                                               int* __restrict__ perm, int N, int nb) {
    __shared__ int cur[DBIN];
    if (threadIdx.x < DBIN) cur[threadIdx.x] = baseD[threadIdx.x * nb + blockIdx.x];
    __syncthreads();
    int i = blockIdx.x * 256 + threadIdx.x;
    if (i < N) {
        int d = min(off[i + 1] - off[i], DBIN - 1);
        int p = atomicAdd(&cur[d], 1);
        perm[p] = i;
    }
}

// ---------------------------------------------------------------------------
// W pre-pack: fp32 W[K][64] -> fp16 B-fragment order for mfma_f32_16x16x32_f16.
// ---------------------------------------------------------------------------
__global__ __launch_bounds__(256) void wpack_k(const float* __restrict__ W, _Float16* __restrict__ P, int total) {
    int o = blockIdx.x * 256 + threadIdx.x;
    if (o >= total) return;
    int j = o & 7, l = (o >> 3) & 63, t = (o >> 9) & 3, s = o >> 11;
    int row = s * 32 + ((l >> 4) << 3) + j;
    int col = (t << 4) + (l & 15);
    P[o] = (_Float16)W[row * 64 + col];
}

// ---------------------------------------------------------------------------
// MFMA GEMM: H[n,64] = X[n,K] @ W[K,64] (fp16 in, fp32 acc) + logits epilogue.
// ---------------------------------------------------------------------------
template<int K, int HEADS>
__global__ __launch_bounds__(256) void gemm_mfma_k(const float* __restrict__ X, const _Float16* __restrict__ P,
                                                   const float* __restrict__ a_s, const float* __restrict__ a_d,
                                                   __half* __restrict__ H, float* __restrict__ ALS,
                                                   float* __restrict__ ALD, int n) {
    __shared__ _Float16 lh[4][16 * 72];   // per-wave transpose buffer, stride 72 halves
    int tid = threadIdx.x;
    int wv = tid >> 6, lane = tid & 63;
    int wid = blockIdx.x * 4 + wv;
    int rowbase = wid << 4;
    if (rowbase >= n) return;
    int q = lane >> 4, cl = lane & 15;

    f16x8 b[K / 32][4];
    const f16x8* Pv = (const f16x8*)P;
#pragma unroll
    for (int s = 0; s < K / 32; s++)
#pragma unroll
        for (int t = 0; t < 4; t++)
            b[s][t] = Pv[(s * 4 + t) * 64 + lane];

    f32x4 c[4];
#pragma unroll
    for (int t = 0; t < 4; t++) c[t] = (f32x4){0.f, 0.f, 0.f, 0.f};

    const float* xrow = X + (size_t)(rowbase + cl) * K + q * 8;
#pragma unroll
    for (int s = 0; s < K / 32; s++) {
        float4 x0 = *(const float4*)(xrow + s * 32);
        float4 x1 = *(const float4*)(xrow + s * 32 + 4);
        f16x8 a;
        a[0] = (_Float16)x0.x; a[1] = (_Float16)x0.y; a[2] = (_Float16)x0.z; a[3] = (_Float16)x0.w;
        a[4] = (_Float16)x1.x; a[5] = (_Float16)x1.y; a[6] = (_Float16)x1.z; a[7] = (_Float16)x1.w;
#pragma unroll
        for (int t = 0; t < 4; t++)
            c[t] = __builtin_amdgcn_mfma_f32_16x16x32_f16(a, b[s][t], c[t], 0, 0, 0);
    }

    if (HEADS == 2) {
        float as0 = a_s[cl], as1 = a_s[16 + cl], as2 = a_s[32 + cl], as3 = a_s[48 + cl];
        float ad0 = a_d[cl], ad1 = a_d[16 + cl], ad2 = a_d[32 + cl], ad3 = a_d[48 + cl];
#pragma unroll
        for (int reg = 0; reg < 4; reg++) {
            float s0 = c[0][reg] * as0 + c[1][reg] * as1;
            float d0 = c[0][reg] * ad0 + c[1][reg] * ad1;
            float s1 = c[2][reg] * as2 + c[3][reg] * as3;
            float d1 = c[2][reg] * ad2 + c[3][reg] * ad3;
#pragma unroll
            for (int m = 1; m <= 8; m <<= 1) {
                s0 += __shfl_xor(s0, m, 64);
                d0 += __shfl_xor(d0, m, 64);
                s1 += __shfl_xor(s1, m, 64);
                d1 += __shfl_xor(d1, m, 64);
            }
            if (cl == 0) {
                int row = rowbase + q * 4 + reg;
                ALS[row * 2]     = s0;
                ALS[row * 2 + 1] = s1;
                ALD[row * 2]     = d0;
                ALD[row * 2 + 1] = d1;
            }
        }
    } else {
        float as0 = a_s[cl], as1 = a_s[16 + cl], as2 = a_s[32 + cl], as3 = a_s[48 + cl];
        float ad0 = a_d[cl], ad1 = a_d[16 + cl], ad2 = a_d[32 + cl], ad3 = a_d[48 + cl];
#pragma unroll
        for (int reg = 0; reg < 4; reg++) {
            float s0 = c[0][reg] * as0 + c[1][reg] * as1 + c[2][reg] * as2 + c[3][reg] * as3;
            float d0 = c[0][reg] * ad0 + c[1][reg] * ad1 + c[2][reg] * ad2 + c[3][reg] * ad3;
#pragma unroll
            for (int m = 1; m <= 8; m <<= 1) {
                s0 += __shfl_xor(s0, m, 64);
                d0 += __shfl_xor(d0, m, 64);
            }
            if (cl == 0) {
                int row = rowbase + q * 4 + reg;
                ALS[row] = s0;
                ALD[row] = d0;
            }
        }
    }

    _Float16* L = lh[wv];
#pragma unroll
    for (int t = 0; t < 4; t++)
#pragma unroll
        for (int reg = 0; reg < 4; reg++)
            L[(q * 4 + reg) * 72 + t * 16 + cl] = (_Float16)c[t][reg];
    __builtin_amdgcn_s_waitcnt(0);
    int rr = lane >> 2, seg = lane & 3;
    uint4 v0 = *(const uint4*)((const char*)L + rr * 144 + seg * 32);
    uint4 v1 = *(const uint4*)((const char*)L + rr * 144 + seg * 32 + 16);
    char* hb = (char*)(H + (size_t)rowbase * 64);
    *(uint4*)(hb + rr * 128 + seg * 32)      = v0;
    *(uint4*)(hb + rr * 128 + seg * 32 + 16) = v1;
}

// ---------------------------------------------------------------------------
// Aggregation: 4 NODES PER WAVE (16 lanes/node, 4 ch/lane as 2xhalf2 = 8B load),
// degree-sorted node assignment (perm) so co-scheduled nodes have equal length.
// 8-deep batches; csr over-read is safe (64-entry zero pad); weights masked.
// ---------------------------------------------------------------------------
template<int HEADS, int RELU>
__global__ __launch_bounds__(256) void aggregate_k(const __half* __restrict__ H, const float* __restrict__ ALS,
                                                   const float* __restrict__ ALD, const int* __restrict__ off,
                                                   const int* __restrict__ csr, const int* __restrict__ perm,
                                                   const float* __restrict__ bias, float* __restrict__ OUT, int n) {
    int lane = threadIdx.x & 63;
    int wv   = threadIdx.x >> 6;
    int c4   = lane & 15;                 // channel quad: channels 4c4 .. 4c4+3
    int idx  = blockIdx.x * 16 + wv * 4 + (lane >> 4);
    bool alive = idx < n;
    int dst = perm[alive ? idx : 0];
    int head = (HEADS == 2) ? (c4 >> 3) : 0;

    int b0 = off[dst];
    int len = alive ? (off[dst + 1] - b0) : 0;
    float ald = ALD[dst * HEADS + head];

    // self-loop contribution
    float e = ALS[dst * HEADS + head] + ald;
    e = fmaxf(e, NEG_SLOPE * e);
    float ee = alive ? __expf(e) : 0.f;
    float den = ee;
    const uint2* Hq = (const uint2*)H;    // H row = 16 uint2 (64 halfs)
    uint2 hv = Hq[dst * 16 + c4];
    float2 hl = __half22float2(*(const __half2*)&hv.x);
    float2 hh = __half22float2(*(const __half2*)&hv.y);
    float a0 = ee * hl.x, a1 = ee * hl.y, a2 = ee * hh.x, a3 = ee * hh.y;

    int lmax = max(len, __shfl_xor(len, 16, 64));
    lmax = max(lmax, __shfl_xor(lmax, 32, 64));

    int j = 0;
    for (; j + 7 < lmax; j += 8) {
        int i0 = b0 + j;
        int s[8];
#pragma unroll
        for (int k = 0; k < 8; k++) s[k] = csr[i0 + k];      // padded: always safe
        float al[8];
#pragma unroll
        for (int k = 0; k < 8; k++) al[k] = ALS[s[k] * HEADS + head];
        uint2 h[8];
#pragma unroll
        for (int k = 0; k < 8; k++) h[k] = Hq[s[k] * 16 + c4];
#pragma unroll
        for (int k = 0; k < 8; k++) {
            float ek = al[k] + ald;
            ek = fmaxf(ek, NEG_SLOPE * ek);
            float wk = (j + k < len) ? __expf(ek) : 0.f;
            float2 l2 = __half22float2(*(const __half2*)&h[k].x);
            float2 h2 = __half22float2(*(const __half2*)&h[k].y);
            den += wk;
            a0 += wk * l2.x; a1 += wk * l2.y;
            a2 += wk * h2.x; a3 += wk * h2.y;
        }
    }
    for (; j < lmax; j++) {
        int s0 = csr[b0 + j];
        float alv = ALS[s0 * HEADS + head];
        uint2 h0 = Hq[s0 * 16 + c4];
        float e0 = alv + ald;
        e0 = fmaxf(e0, NEG_SLOPE * e0);
        float w0 = (j < len) ? __expf(e0) : 0.f;
        float2 l2 = __half22float2(*(const __half2*)&h0.x);
        float2 h2 = __half22float2(*(const __half2*)&h0.y);
        den += w0;
        a0 += w0 * l2.x; a1 += w0 * l2.y;
        a2 += w0 * h2.x; a3 += w0 * h2.y;
    }

    if (alive) {
        float4 bi = ((const float4*)bias)[c4];
        float rd = 1.f / den;
        float o0 = a0 * rd + bi.x;
        float o1 = a1 * rd + bi.y;
        float o2 = a2 * rd + bi.z;
        float o3 = a3 * rd + bi.w;
        if (RELU) {
            o0 = fmaxf(o0, 0.f); o1 = fmaxf(o1, 0.f);
            o2 = fmaxf(o2, 0.f); o3 = fmaxf(o3, 0.f);
        }
        ((float4*)OUT)[dst * 16 + c4] = make_float4(o0, o1, o2, o3);
    }
}

// ---------------------------------------------------------------------------
extern "C" void kernel_launch(void* const* d_in, const int* in_sizes, int n_in,
                              void* d_out, int out_size, void* d_ws, size_t ws_size,
                              hipStream_t stream) {
    const float* x   = (const float*)d_in[0];
    const int*   ei  = (const int*)  d_in[1];
    const float* W1  = (const float*)d_in[2];
    const float* as1 = (const float*)d_in[3];
    const float* ad1 = (const float*)d_in[4];
    const float* b1  = (const float*)d_in[5];
    const float* W2  = (const float*)d_in[6];
    const float* as2 = (const float*)d_in[7];
    const float* ad2 = (const float*)d_in[8];
    const float* b2  = (const float*)d_in[9];
    const float* W3  = (const float*)d_in[10];
    const float* as3 = (const float*)d_in[11];
    const float* ad3 = (const float*)d_in[12];
    const float* b3  = (const float*)d_in[13];

    const int N = in_sizes[0] / IN_CH;
    const int E = in_sizes[1] / 2;
    const int NBUCK = (N + NPB - 1) >> BSH;              // 196 (<=256)
    const int NEB   = (E + EPB - 1) / EPB;               // 196 binning blocks
    const int NT    = NBUCK * NEB;                       // countsT elements (~38k)
    const int NB    = (N + 255) / 256;                   // node blocks (391)
    const int ND    = DBIN * NB;                         // degree-hist elements (~25k)

    // workspace carve (256B aligned)
    char* p = (char*)d_ws;
    auto carve = [&](size_t bytes) {
        char* r = p;
        p += (bytes + 255) & ~(size_t)255;
        return r;
    };
    __half*    hbuf    = (__half*)   carve((size_t)N * HC * 2);
    float*     obuf    = (float*)    carve((size_t)N * HC * 4);
    float*     als     = (float*)    carve((size_t)N * 2 * 4);
    float*     ald     = (float*)    carve((size_t)N * 2 * 4);
    int*       off     = (int*)      carve((size_t)(N + 1) * 4);
    int*       tmp     = (int*)      carve((size_t)NT * 4);
    int*       bsum    = (int*)      carve((size_t)((NT + 255) / 256 + 1) * 4);
    int*       csr     = (int*)      carve((size_t)(E + 64) * 4);   // +64 zero pad
    unsigned*  pairs   = (unsigned*) carve((size_t)E * 4);
    int*       countsT = (int*)      carve((size_t)NT * 4);
    int*       baseT   = (int*)      carve((size_t)NT * 4);
    int*       countsD = (int*)      carve((size_t)ND * 4);
    int*       baseD   = (int*)      carve((size_t)ND * 4);
    int*       perm    = (int*)      carve((size_t)N * 4);
    _Float16*  wp1     = (_Float16*) carve((size_t)IN_CH * 64 * 2);
    _Float16*  wp2     = (_Float16*) carve((size_t)64 * 64 * 2);
    _Float16*  wp3     = (_Float16*) carve((size_t)64 * 64 * 2);

    const int NTB = (NT + 255) / 256;     // countsT-scan blocks (<=512)
    const int NDB = (ND + 255) / 256;     // countsD-scan blocks (<=512)
    const int NW4 = (N + 15) / 16;        // aggregate: 4 nodes/wave, 4 waves/block
    const int NBM = (N / 16 + 3) / 4;     // mfma gemm: 16 rows/wave, 4 waves/block

    // ---- W fragment pre-pack (fp32 -> fp16 B-frag order) ----
    wpack_k<<<(IN_CH * 64) / 256, 256, 0, stream>>>(W1, wp1, IN_CH * 64);
    wpack_k<<<(64 * 64) / 256, 256, 0, stream>>>(W2, wp2, 64 * 64);
    wpack_k<<<(64 * 64) / 256, 256, 0, stream>>>(W3, wp3, 64 * 64);

    // ---- CSR build (shared by all 3 layers); off[] fused into pass B ----
    csortA1_k<<<NEB, 256, 0, stream>>>(ei, countsT, E, NBUCK, NEB);
    scan1_k  <<<NTB, 256, 0, stream>>>(countsT, tmp, bsum, NT);
    scan2_k  <<<1, 512, 0, stream>>>(bsum, NTB);
    combine_k<<<NTB, 256, 0, stream>>>(tmp, bsum, baseT, NT);
    csortA3_k<<<NEB, 256, 0, stream>>>(ei, baseT, pairs, E, NBUCK, NEB);
    csortB2_k<<<NBUCK, 256, 0, stream>>>(pairs, baseT, off, csr, N, E, NBUCK, NEB);

    // ---- node degree-sort (for aggregate wave load balance) ----
    dhist_k  <<<NB, 256, 0, stream>>>(off, countsD, N, NB);
    scan1_k  <<<NDB, 256, 0, stream>>>(countsD, tmp, bsum, ND);
    scan2_k  <<<1, 512, 0, stream>>>(bsum, NDB);
    combine_k<<<NDB, 256, 0, stream>>>(tmp, bsum, baseD, ND);
    drank_k  <<<NB, 256, 0, stream>>>(off, baseD, perm, N, NB);

    // ---- Layer 1: IN=128 -> 2x32 concat, relu ----
    gemm_mfma_k<128, 2><<<NBM, 256, 0, stream>>>(x, wp1, as1, ad1, hbuf, als, ald, N);
    aggregate_k<2, 1>  <<<NW4, 256, 0, stream>>>(hbuf, als, ald, off, csr, perm, b1, obuf, N);

    // ---- Layer 2: 64 -> 2x32 concat, relu ----
    gemm_mfma_k<64, 2><<<NBM, 256, 0, stream>>>(obuf, wp2, as2, ad2, hbuf, als, ald, N);
    aggregate_k<2, 1> <<<NW4, 256, 0, stream>>>(hbuf, als, ald, off, csr, perm, b2, obuf, N);

    // ---- Layer 3: 64 -> 64, 1 head, mean(=identity), no relu ----
    gemm_mfma_k<64, 1><<<NBM, 256, 0, stream>>>(obuf, wp3, as3, ad3, hbuf, als, ald, N);
    aggregate_k<1, 0> <<<NW4, 256, 0, stream>>>(hbuf, als, ald, off, csr, perm, b3, (float*)d_out, N);
}

// Round 13
// 333.698 us; speedup vs baseline: 1.4854x; 1.0032x over previous
//
#include <hip/hip_runtime.h>
#include <hip/hip_fp16.h>

// Problem constants (match reference)
#define IN_CH   128
#define HC      64      // channels per node at every layer boundary
#define NEG_SLOPE 0.2f

// counting-sort parameters: bucket = dst >> BSH (<=256 buckets), src in low 17 bits
#define BSH   9
#define NPB   512       // nodes per bucket = 1 << BSH
#define EPB   8192      // edges per binning block
#define DBIN  64        // degree bins for node degree-sort (clamped)

typedef __attribute__((ext_vector_type(8))) _Float16 f16x8;
typedef __attribute__((ext_vector_type(4))) float    f32x4;

// ---------------------------------------------------------------------------
// generic block scan kernels
// ---------------------------------------------------------------------------
__global__ __launch_bounds__(256) void scan1_k(const int* __restrict__ deg, int* __restrict__ tmp,
                                               int* __restrict__ bsum, int n) {
    __shared__ int s[256];
    int tid = threadIdx.x;
    int i = blockIdx.x * 256 + tid;
    int v = (i < n) ? deg[i] : 0;
    s[tid] = v; __syncthreads();
    for (int o = 1; o < 256; o <<= 1) {
        int t = (tid >= o) ? s[tid - o] : 0;
        __syncthreads();
        s[tid] += t;
        __syncthreads();
    }
    if (i < n) tmp[i] = s[tid] - v;            // exclusive within block
    if (tid == 255) bsum[blockIdx.x] = s[255]; // block total
}

__global__ __launch_bounds__(512) void scan2_k(int* __restrict__ bsum, int nb) {
    __shared__ int s[512];
    int tid = threadIdx.x;
    int v = (tid < nb) ? bsum[tid] : 0;
    s[tid] = v; __syncthreads();
    for (int o = 1; o < 512; o <<= 1) {
        int t = (tid >= o) ? s[tid - o] : 0;
        __syncthreads();
        s[tid] += t;
        __syncthreads();
    }
    if (tid < nb) bsum[tid] = s[tid] - v;      // exclusive block offsets
}

__global__ __launch_bounds__(256) void combine_k(const int* __restrict__ tmp, const int* __restrict__ bsum,
                                                 int* __restrict__ base, int n) {
    int i = blockIdx.x * 256 + threadIdx.x;
    if (i < n) base[i] = tmp[i] + bsum[blockIdx.x];
}

// ---------------------------------------------------------------------------
// counting sort of edges by dst bucket — LDS-binned, no global atomic contention
// ---------------------------------------------------------------------------
__global__ __launch_bounds__(256) void csortA1_k(const int* __restrict__ ei, int* __restrict__ countsT,
                                                 int E, int nbuck, int neb) {
    __shared__ int cnt[256];
    cnt[threadIdx.x] = 0;
    __syncthreads();
    int base = blockIdx.x * EPB;
#pragma unroll
    for (int k = 0; k < EPB / 256; k++) {
        int i = base + k * 256 + threadIdx.x;
        if (i < E) atomicAdd(&cnt[ei[E + i] >> BSH], 1);
    }
    __syncthreads();
    if (threadIdx.x < nbuck) countsT[threadIdx.x * neb + blockIdx.x] = cnt[threadIdx.x];
}

__global__ __launch_bounds__(256) void csortA3_k(const int* __restrict__ ei, const int* __restrict__ baseT,
                                                 unsigned* __restrict__ pairs, int E, int nbuck, int neb) {
    __shared__ int cur[256];
    if (threadIdx.x < nbuck) cur[threadIdx.x] = baseT[threadIdx.x * neb + blockIdx.x];
    __syncthreads();
    int base = blockIdx.x * EPB;
#pragma unroll
    for (int k = 0; k < EPB / 256; k++) {
        int i = base + k * 256 + threadIdx.x;
        if (i < E) {
            int d = ei[E + i];
            int s = ei[i];
            int p = atomicAdd(&cur[d >> BSH], 1);
            pairs[p] = ((unsigned)(d & (NPB - 1)) << 17) | (unsigned)s;
        }
    }
}

// B: one block per bucket. Fused: per-node LDS histogram -> block scan ->
// node offsets (off[]) -> LDS-cursor ranking -> csr write. Zero-pads csr[E..E+63].
__global__ __launch_bounds__(256) void csortB2_k(const unsigned* __restrict__ pairs, const int* __restrict__ baseT,
                                                 int* __restrict__ off, int* __restrict__ csr,
                                                 int N, int E, int nbuck, int neb) {
    __shared__ int cnt[NPB];
    __shared__ int cur[NPB];
    __shared__ int ps[256];
    int b = blockIdx.x;
    int tid = threadIdx.x;
    int rs = baseT[b * neb];
    int re = (b + 1 < nbuck) ? baseT[(b + 1) * neb] : E;

    cnt[tid] = 0; cnt[tid + 256] = 0;
    __syncthreads();
    for (int j = rs + tid; j < re; j += 256)
        atomicAdd(&cnt[pairs[j] >> 17], 1);
    __syncthreads();

    int c0 = cnt[2 * tid], c1 = cnt[2 * tid + 1];
    int pair = c0 + c1;
    ps[tid] = pair;
    __syncthreads();
    for (int o = 1; o < 256; o <<= 1) {
        int t = (tid >= o) ? ps[tid - o] : 0;
        __syncthreads();
        ps[tid] += t;
        __syncthreads();
    }
    int base0 = rs + ps[tid] - pair;
    int n0 = b * NPB + 2 * tid;
    cur[2 * tid] = base0;
    cur[2 * tid + 1] = base0 + c0;
    if (n0 < N)     off[n0] = base0;
    if (n0 + 1 < N) off[n0 + 1] = base0 + c0;
    if (b == nbuck - 1 && tid == 0) off[N] = E;
    if (b == nbuck - 1 && tid < 64) csr[E + tid] = 0;   // pad for batched reads
    __syncthreads();

    for (int j = rs + tid; j < re; j += 256) {
        unsigned v = pairs[j];
        int p = atomicAdd(&cur[v >> 17], 1);
        csr[p] = (int)(v & 0x1FFFF);
    }
}

// ---------------------------------------------------------------------------
// Node degree-sort (counting sort by clamped degree)
// ---------------------------------------------------------------------------
__global__ __launch_bounds__(256) void dhist_k(const int* __restrict__ off, int* __restrict__ countsD,
                                               int N, int nb) {
    __shared__ int cnt[DBIN];
    if (threadIdx.x < DBIN) cnt[threadIdx.x] = 0;
    __syncthreads();
    int i = blockIdx.x * 256 + threadIdx.x;
    if (i < N) {
        int d = min(off[i + 1] - off[i], DBIN - 1);
        atomicAdd(&cnt[d], 1);
    }
    __syncthreads();
    if (threadIdx.x < DBIN) countsD[threadIdx.x * nb + blockIdx.x] = cnt[threadIdx.x];
}

__global__ __launch_bounds__(256) void drank_k(const int* __restrict__ off, const int* __restrict__ baseD,
                                               int* __restrict__ perm, int N, int nb) {
    __shared__ int cur[DBIN];
    if (threadIdx.x < DBIN) cur[threadIdx.x] = baseD[threadIdx.x * nb + blockIdx.x];
    __syncthreads();
    int i = blockIdx.x * 256 + threadIdx.x;
    if (i < N) {
        int d = min(off[i + 1] - off[i], DBIN - 1);
        int p = atomicAdd(&cur[d], 1);
        perm[p] = i;
    }
}

// ---------------------------------------------------------------------------
// W pre-pack: fp32 W[K][64] -> fp16 B-fragment order for mfma_f32_16x16x32_f16.
// ---------------------------------------------------------------------------
__global__ __launch_bounds__(256) void wpack_k(const float* __restrict__ W, _Float16* __restrict__ P, int total) {
    int o = blockIdx.x * 256 + threadIdx.x;
    if (o >= total) return;
    int j = o & 7, l = (o >> 3) & 63, t = (o >> 9) & 3, s = o >> 11;
    int row = s * 32 + ((l >> 4) << 3) + j;
    int col = (t << 4) + (l & 15);
    P[o] = (_Float16)W[row * 64 + col];
}

// ---------------------------------------------------------------------------
// MFMA GEMM: H[n,64] = X[n,K] @ W[K,64] + logits epilogue.
// F16IN: X is fp16 (layer 2/3, direct A-frag 16B loads, no cvt).
// ---------------------------------------------------------------------------
template<int K, int HEADS, bool F16IN>
__global__ __launch_bounds__(256) void gemm_mfma_k(const void* __restrict__ Xv, const _Float16* __restrict__ P,
                                                   const float* __restrict__ a_s, const float* __restrict__ a_d,
                                                   __half* __restrict__ H, float* __restrict__ ALS,
                                                   float* __restrict__ ALD, int n) {
    __shared__ _Float16 lh[4][16 * 72];   // per-wave transpose buffer, stride 72 halves
    int tid = threadIdx.x;
    int wv = tid >> 6, lane = tid & 63;
    int wid = blockIdx.x * 4 + wv;
    int rowbase = wid << 4;
    if (rowbase >= n) return;
    int q = lane >> 4, cl = lane & 15;

    f16x8 b[K / 32][4];
    const f16x8* Pv = (const f16x8*)P;
#pragma unroll
    for (int s = 0; s < K / 32; s++)
#pragma unroll
        for (int t = 0; t < 4; t++)
            b[s][t] = Pv[(s * 4 + t) * 64 + lane];

    f32x4 c[4];
#pragma unroll
    for (int t = 0; t < 4; t++) c[t] = (f32x4){0.f, 0.f, 0.f, 0.f};

#pragma unroll
    for (int s = 0; s < K / 32; s++) {
        f16x8 a;
        if (F16IN) {
            const _Float16* xrow = (const _Float16*)Xv + (size_t)(rowbase + cl) * K + q * 8;
            a = *(const f16x8*)(xrow + s * 32);
        } else {
            const float* xrow = (const float*)Xv + (size_t)(rowbase + cl) * K + q * 8;
            float4 x0 = *(const float4*)(xrow + s * 32);
            float4 x1 = *(const float4*)(xrow + s * 32 + 4);
            a[0] = (_Float16)x0.x; a[1] = (_Float16)x0.y; a[2] = (_Float16)x0.z; a[3] = (_Float16)x0.w;
            a[4] = (_Float16)x1.x; a[5] = (_Float16)x1.y; a[6] = (_Float16)x1.z; a[7] = (_Float16)x1.w;
        }
#pragma unroll
        for (int t = 0; t < 4; t++)
            c[t] = __builtin_amdgcn_mfma_f32_16x16x32_f16(a, b[s][t], c[t], 0, 0, 0);
    }

    if (HEADS == 2) {
        float as0 = a_s[cl], as1 = a_s[16 + cl], as2 = a_s[32 + cl], as3 = a_s[48 + cl];
        float ad0 = a_d[cl], ad1 = a_d[16 + cl], ad2 = a_d[32 + cl], ad3 = a_d[48 + cl];
#pragma unroll
        for (int reg = 0; reg < 4; reg++) {
            float s0 = c[0][reg] * as0 + c[1][reg] * as1;
            float d0 = c[0][reg] * ad0 + c[1][reg] * ad1;
            float s1 = c[2][reg] * as2 + c[3][reg] * as3;
            float d1 = c[2][reg] * ad2 + c[3][reg] * ad3;
#pragma unroll
            for (int m = 1; m <= 8; m <<= 1) {
                s0 += __shfl_xor(s0, m, 64);
                d0 += __shfl_xor(d0, m, 64);
                s1 += __shfl_xor(s1, m, 64);
                d1 += __shfl_xor(d1, m, 64);
            }
            if (cl == 0) {
                int row = rowbase + q * 4 + reg;
                ALS[row * 2]     = s0;
                ALS[row * 2 + 1] = s1;
                ALD[row * 2]     = d0;
                ALD[row * 2 + 1] = d1;
            }
        }
    } else {
        float as0 = a_s[cl], as1 = a_s[16 + cl], as2 = a_s[32 + cl], as3 = a_s[48 + cl];
        float ad0 = a_d[cl], ad1 = a_d[16 + cl], ad2 = a_d[32 + cl], ad3 = a_d[48 + cl];
#pragma unroll
        for (int reg = 0; reg < 4; reg++) {
            float s0 = c[0][reg] * as0 + c[1][reg] * as1 + c[2][reg] * as2 + c[3][reg] * as3;
            float d0 = c[0][reg] * ad0 + c[1][reg] * ad1 + c[2][reg] * ad2 + c[3][reg] * ad3;
#pragma unroll
            for (int m = 1; m <= 8; m <<= 1) {
                s0 += __shfl_xor(s0, m, 64);
                d0 += __shfl_xor(d0, m, 64);
            }
            if (cl == 0) {
                int row = rowbase + q * 4 + reg;
                ALS[row] = s0;
                ALD[row] = d0;
            }
        }
    }

    _Float16* L = lh[wv];
#pragma unroll
    for (int t = 0; t < 4; t++)
#pragma unroll
        for (int reg = 0; reg < 4; reg++)
            L[(q * 4 + reg) * 72 + t * 16 + cl] = (_Float16)c[t][reg];
    __builtin_amdgcn_s_waitcnt(0);
    int rr = lane >> 2, seg = lane & 3;
    uint4 v0 = *(const uint4*)((const char*)L + rr * 144 + seg * 32);
    uint4 v1 = *(const uint4*)((const char*)L + rr * 144 + seg * 32 + 16);
    char* hb = (char*)(H + (size_t)rowbase * 64);
    *(uint4*)(hb + rr * 128 + seg * 32)      = v0;
    *(uint4*)(hb + rr * 128 + seg * 32 + 16) = v1;
}

// ---------------------------------------------------------------------------
// Aggregation: 8 NODES PER WAVE (8 lanes/node, 8 ch/lane via 16B uint4 loads),
// degree-sorted node assignment; 8-deep batches; csr 64-entry zero pad.
// OUTF16: write fp16 (layer boundary — identical rounding to gemm's own cvt).
// ---------------------------------------------------------------------------
template<int HEADS, int RELU, bool OUTF16>
__global__ __launch_bounds__(256) void aggregate_k(const __half* __restrict__ H, const float* __restrict__ ALS,
                                                   const float* __restrict__ ALD, const int* __restrict__ off,
                                                   const int* __restrict__ csr, const int* __restrict__ perm,
                                                   const float* __restrict__ bias, void* __restrict__ OUT, int n) {
    int lane = threadIdx.x & 63;
    int wv   = threadIdx.x >> 6;
    int c8   = lane & 7;                  // channel octet: channels 8c8 .. 8c8+7
    int idx  = blockIdx.x * 32 + wv * 8 + (lane >> 3);
    bool alive = idx < n;
    int dst = perm[alive ? idx : 0];
    int head = (HEADS == 2) ? (c8 >> 2) : 0;

    int b0 = off[dst];
    int len = alive ? (off[dst + 1] - b0) : 0;
    float ald = ALD[dst * HEADS + head];

    // self-loop contribution
    float e = ALS[dst * HEADS + head] + ald;
    e = fmaxf(e, NEG_SLOPE * e);
    float ee = alive ? __expf(e) : 0.f;
    float den = ee;
    const uint4* Ho = (const uint4*)H;    // H row = 8 uint4 (64 halfs)
    uint4 hv = Ho[dst * 8 + c8];
    float acc[8];
    {
        float2 p0 = __half22float2(*(const __half2*)&hv.x);
        float2 p1 = __half22float2(*(const __half2*)&hv.y);
        float2 p2 = __half22float2(*(const __half2*)&hv.z);
        float2 p3 = __half22float2(*(const __half2*)&hv.w);
        acc[0] = ee * p0.x; acc[1] = ee * p0.y; acc[2] = ee * p1.x; acc[3] = ee * p1.y;
        acc[4] = ee * p2.x; acc[5] = ee * p2.y; acc[6] = ee * p3.x; acc[7] = ee * p3.y;
    }

    int lmax = max(len, __shfl_xor(len, 8, 64));
    lmax = max(lmax, __shfl_xor(lmax, 16, 64));
    lmax = max(lmax, __shfl_xor(lmax, 32, 64));

    int j = 0;
    for (; j + 7 < lmax; j += 8) {
        int i0 = b0 + j;
        int s[8];
#pragma unroll
        for (int k = 0; k < 8; k++) s[k] = csr[i0 + k];      // padded: always safe
        float al[8];
#pragma unroll
        for (int k = 0; k < 8; k++) al[k] = ALS[s[k] * HEADS + head];
        uint4 h[8];
#pragma unroll
        for (int k = 0; k < 8; k++) h[k] = Ho[s[k] * 8 + c8];
#pragma unroll
        for (int k = 0; k < 8; k++) {
            float ek = al[k] + ald;
            ek = fmaxf(ek, NEG_SLOPE * ek);
            float wk = (j + k < len) ? __expf(ek) : 0.f;
            den += wk;
            float2 p0 = __half22float2(*(const __half2*)&h[k].x);
            float2 p1 = __half22float2(*(const __half2*)&h[k].y);
            float2 p2 = __half22float2(*(const __half2*)&h[k].z);
            float2 p3 = __half22float2(*(const __half2*)&h[k].w);
            acc[0] += wk * p0.x; acc[1] += wk * p0.y; acc[2] += wk * p1.x; acc[3] += wk * p1.y;
            acc[4] += wk * p2.x; acc[5] += wk * p2.y; acc[6] += wk * p3.x; acc[7] += wk * p3.y;
        }
    }
    for (; j < lmax; j++) {
        int s0 = csr[b0 + j];
        float alv = ALS[s0 * HEADS + head];
        uint4 h0 = Ho[s0 * 8 + c8];
        float e0 = alv + ald;
        e0 = fmaxf(e0, NEG_SLOPE * e0);
        float w0 = (j < len) ? __expf(e0) : 0.f;
        den += w0;
        float2 p0 = __half22float2(*(const __half2*)&h0.x);
        float2 p1 = __half22float2(*(const __half2*)&h0.y);
        float2 p2 = __half22float2(*(const __half2*)&h0.z);
        float2 p3 = __half22float2(*(const __half2*)&h0.w);
        acc[0] += w0 * p0.x; acc[1] += w0 * p0.y; acc[2] += w0 * p1.x; acc[3] += w0 * p1.y;
        acc[4] += w0 * p2.x; acc[5] += w0 * p2.y; acc[6] += w0 * p3.x; acc[7] += w0 * p3.y;
    }

    if (alive) {
        float4 b0v = ((const float4*)bias)[2 * c8];
        float4 b1v = ((const float4*)bias)[2 * c8 + 1];
        float rd = 1.f / den;
        float o[8];
        o[0] = acc[0] * rd + b0v.x; o[1] = acc[1] * rd + b0v.y;
        o[2] = acc[2] * rd + b0v.z; o[3] = acc[3] * rd + b0v.w;
        o[4] = acc[4] * rd + b1v.x; o[5] = acc[5] * rd + b1v.y;
        o[6] = acc[6] * rd + b1v.z; o[7] = acc[7] * rd + b1v.w;
        if (RELU) {
#pragma unroll
            for (int k = 0; k < 8; k++) o[k] = fmaxf(o[k], 0.f);
        }
        if (OUTF16) {
            __half2 q0 = __floats2half2_rn(o[0], o[1]);
            __half2 q1 = __floats2half2_rn(o[2], o[3]);
            __half2 q2 = __floats2half2_rn(o[4], o[5]);
            __half2 q3 = __floats2half2_rn(o[6], o[7]);
            uint4 u;
            u.x = *(unsigned*)&q0; u.y = *(unsigned*)&q1;
            u.z = *(unsigned*)&q2; u.w = *(unsigned*)&q3;
            ((uint4*)OUT)[dst * 8 + c8] = u;
        } else {
            ((float4*)OUT)[dst * 16 + 2 * c8]     = make_float4(o[0], o[1], o[2], o[3]);
            ((float4*)OUT)[dst * 16 + 2 * c8 + 1] = make_float4(o[4], o[5], o[6], o[7]);
        }
    }
}

// ---------------------------------------------------------------------------
extern "C" void kernel_launch(void* const* d_in, const int* in_sizes, int n_in,
                              void* d_out, int out_size, void* d_ws, size_t ws_size,
                              hipStream_t stream) {
    const float* x   = (const float*)d_in[0];
    const int*   ei  = (const int*)  d_in[1];
    const float* W1  = (const float*)d_in[2];
    const float* as1 = (const float*)d_in[3];
    const float* ad1 = (const float*)d_in[4];
    const float* b1  = (const float*)d_in[5];
    const float* W2  = (const float*)d_in[6];
    const float* as2 = (const float*)d_in[7];
    const float* ad2 = (const float*)d_in[8];
    const float* b2  = (const float*)d_in[9];
    const float* W3  = (const float*)d_in[10];
    const float* as3 = (const float*)d_in[11];
    const float* ad3 = (const float*)d_in[12];
    const float* b3  = (const float*)d_in[13];

    const int N = in_sizes[0] / IN_CH;
    const int E = in_sizes[1] / 2;
    const int NBUCK = (N + NPB - 1) >> BSH;              // 196 (<=256)
    const int NEB   = (E + EPB - 1) / EPB;               // 196 binning blocks
    const int NT    = NBUCK * NEB;                       // countsT elements (~38k)
    const int NB    = (N + 255) / 256;                   // node blocks (391)
    const int ND    = DBIN * NB;                         // degree-hist elements (~25k)

    // workspace carve (256B aligned)
    char* p = (char*)d_ws;
    auto carve = [&](size_t bytes) {
        char* r = p;
        p += (bytes + 255) & ~(size_t)255;
        return r;
    };
    __half*    hbuf    = (__half*)   carve((size_t)N * HC * 2);
    __half*    obuf    = (__half*)   carve((size_t)N * HC * 2);   // fp16 layer boundary
    float*     als     = (float*)    carve((size_t)N * 2 * 4);
    float*     ald     = (float*)    carve((size_t)N * 2 * 4);
    int*       off     = (int*)      carve((size_t)(N + 1) * 4);
    int*       tmp     = (int*)      carve((size_t)NT * 4);
    int*       bsum    = (int*)      carve((size_t)((NT + 255) / 256 + 1) * 4);
    int*       csr     = (int*)      carve((size_t)(E + 64) * 4);   // +64 zero pad
    unsigned*  pairs   = (unsigned*) carve((size_t)E * 4);
    int*       countsT = (int*)      carve((size_t)NT * 4);
    int*       baseT   = (int*)      carve((size_t)NT * 4);
    int*       countsD = (int*)      carve((size_t)ND * 4);
    int*       baseD   = (int*)      carve((size_t)ND * 4);
    int*       perm    = (int*)      carve((size_t)N * 4);
    _Float16*  wp1     = (_Float16*) carve((size_t)IN_CH * 64 * 2);
    _Float16*  wp2     = (_Float16*) carve((size_t)64 * 64 * 2);
    _Float16*  wp3     = (_Float16*) carve((size_t)64 * 64 * 2);

    const int NTB = (NT + 255) / 256;     // countsT-scan blocks (<=512)
    const int NDB = (ND + 255) / 256;     // countsD-scan blocks (<=512)
    const int NW8 = (N + 31) / 32;        // aggregate: 8 nodes/wave, 4 waves/block
    const int NBM = (N / 16 + 3) / 4;     // mfma gemm: 16 rows/wave, 4 waves/block

    // ---- W fragment pre-pack (fp32 -> fp16 B-frag order) ----
    wpack_k<<<(IN_CH * 64) / 256, 256, 0, stream>>>(W1, wp1, IN_CH * 64);
    wpack_k<<<(64 * 64) / 256, 256, 0, stream>>>(W2, wp2, 64 * 64);
    wpack_k<<<(64 * 64) / 256, 256, 0, stream>>>(W3, wp3, 64 * 64);

    // ---- CSR build (shared by all 3 layers); off[] fused into pass B ----
    csortA1_k<<<NEB, 256, 0, stream>>>(ei, countsT, E, NBUCK, NEB);
    scan1_k  <<<NTB, 256, 0, stream>>>(countsT, tmp, bsum, NT);
    scan2_k  <<<1, 512, 0, stream>>>(bsum, NTB);
    combine_k<<<NTB, 256, 0, stream>>>(tmp, bsum, baseT, NT);
    csortA3_k<<<NEB, 256, 0, stream>>>(ei, baseT, pairs, E, NBUCK, NEB);
    csortB2_k<<<NBUCK, 256, 0, stream>>>(pairs, baseT, off, csr, N, E, NBUCK, NEB);

    // ---- node degree-sort (for aggregate wave load balance) ----
    dhist_k  <<<NB, 256, 0, stream>>>(off, countsD, N, NB);
    scan1_k  <<<NDB, 256, 0, stream>>>(countsD, tmp, bsum, ND);
    scan2_k  <<<1, 512, 0, stream>>>(bsum, NDB);
    combine_k<<<NDB, 256, 0, stream>>>(tmp, bsum, baseD, ND);
    drank_k  <<<NB, 256, 0, stream>>>(off, baseD, perm, N, NB);

    // ---- Layer 1: IN=128 -> 2x32 concat, relu ----
    gemm_mfma_k<128, 2, false><<<NBM, 256, 0, stream>>>(x, wp1, as1, ad1, hbuf, als, ald, N);
    aggregate_k<2, 1, true>   <<<NW8, 256, 0, stream>>>(hbuf, als, ald, off, csr, perm, b1, obuf, N);

    // ---- Layer 2: 64 -> 2x32 concat, relu ----
    gemm_mfma_k<64, 2, true><<<NBM, 256, 0, stream>>>(obuf, wp2, as2, ad2, hbuf, als, ald, N);
    aggregate_k<2, 1, true> <<<NW8, 256, 0, stream>>>(hbuf, als, ald, off, csr, perm, b2, obuf, N);

    // ---- Layer 3: 64 -> 64, 1 head, mean(=identity), no relu ----
    gemm_mfma_k<64, 1, true><<<NBM, 256, 0, stream>>>(obuf, wp3, as3, ad3, hbuf, als, ald, N);
    aggregate_k<1, 0, false><<<NW8, 256, 0, stream>>>(hbuf, als, ald, off, csr, perm, b3, d_out, N);
}